// Round 1
// baseline (612.777 us; speedup 1.0000x reference)
//
#include <hip/hip_runtime.h>
#include <math.h>

#define Bdim 128
#define Ldim 16384
#define Cdim 12
#define Ddim 128
#define Tdim 256
#define TOn  8
#define TIn  64
#define Sn   183
#define G3   384
#define DENOMF 187392.0f
#define NEG_INF -3.402823466e38f

// ---------------- workspace layout (floats) ----------------
#define OFF_ENC 0
#define OFF_CTX (OFF_ENC + Tdim*Bdim*Ddim)     // 4194304
#define OFF_GI  (OFF_CTX + Tdim*Bdim*Ddim)     // 8388608
#define OFF_BC  (OFF_GI  + Tdim*Bdim*G3)      // 20971520  (conv weight, [kt*12+c][d])
#define OFF_WT  (OFF_BC  + 768*128)            // 21069824  (W_ih^T, [k][n])
#define OFF_LP  (OFF_WT  + 128*384)            // 21118976  (loss partials, 1464)
#define OFF_CP  (OFF_LP  + TOn*Sn)             // corr partials, 1464
// total = 21121904 floats = 84.5 MB

__device__ __forceinline__ float frcp(float x) { return __builtin_amdgcn_rcpf(x); }

// ---------------- prep: weight transposes ----------------
__global__ __launch_bounds__(256) void k_prep(const float* __restrict__ conv_w,
                                              float* __restrict__ Bc,
                                              const float* __restrict__ W_ih,
                                              float* __restrict__ Wt) {
    int id = blockIdx.x * 256 + threadIdx.x;
    if (id < 768 * 128) {
        int klin = id >> 7, d = id & 127;       // klin = kt*12 + c
        int kt = klin / 12, c = klin % 12;
        Bc[id] = conv_w[d * 768 + c * 64 + kt];
    }
    if (id < 128 * 384) {
        int k = id / 384, n = id % 384;
        Wt[id] = W_ih[n * 128 + k];
    }
}

// ---------------- conv as GEMM: enc[t][b][d] = relu(X_slice . Bc + conv_b) ----------------
// one block per t; A rows = 128 b's (rotated LDS), B = Bc chunk [k][d]
__global__ __launch_bounds__(256) void k_conv(const float* __restrict__ X,
                                              const float* __restrict__ Bc,
                                              const float* __restrict__ conv_b,
                                              float* __restrict__ enc) {
    const int t = blockIdx.x;
    __shared__ float As[128 * 64];   // [r][(k + 4*(r>>3)) & 63]
    __shared__ float Bs[64 * 128];   // [k][d]
    const int tid = threadIdx.x;
    const int ty = tid >> 4, tx = tid & 15;

    float acc[8][8];
#pragma unroll
    for (int i = 0; i < 8; ++i)
#pragma unroll
        for (int j = 0; j < 8; ++j) acc[i][j] = 0.f;

    for (int kc = 0; kc < 768; kc += 64) {
        __syncthreads();
#pragma unroll
        for (int it = 0; it < 8; ++it) {          // stage A: 128 rows x 64
            int lin = tid + it * 256;             // 0..2047
            int r = lin >> 4, k4 = lin & 15;
            float4 v = *(const float4*)(X + (size_t)r * (Ldim * Cdim) + t * 768 + kc + k4 * 4);
            int col = (k4 * 4 + ((r >> 3) << 2)) & 63;
            *(float4*)(As + r * 64 + col) = v;
        }
#pragma unroll
        for (int it = 0; it < 8; ++it) {          // stage B: 64 x 128
            int lin = tid + it * 256;
            int k = lin >> 5, d4 = lin & 31;
            float4 v = *(const float4*)(Bc + (size_t)(kc + k) * 128 + d4 * 4);
            *(float4*)(Bs + k * 128 + d4 * 4) = v;
        }
        __syncthreads();

        for (int k = 0; k < 64; ++k) {
            float a[8], bb[8];
            const int acol = (k + 4 * ty) & 63;
#pragma unroll
            for (int i = 0; i < 8; ++i) a[i] = As[(ty * 8 + i) * 64 + acol];
            float4 b0 = *(const float4*)(Bs + k * 128 + tx * 8);
            float4 b1 = *(const float4*)(Bs + k * 128 + tx * 8 + 4);
            bb[0] = b0.x; bb[1] = b0.y; bb[2] = b0.z; bb[3] = b0.w;
            bb[4] = b1.x; bb[5] = b1.y; bb[6] = b1.z; bb[7] = b1.w;
#pragma unroll
            for (int i = 0; i < 8; ++i)
#pragma unroll
                for (int j = 0; j < 8; ++j) acc[i][j] = fmaf(a[i], bb[j], acc[i][j]);
        }
    }
    // epilogue: bias + relu + store enc[t][b][d]
    float4 cb0 = *(const float4*)(conv_b + tx * 8);
    float4 cb1 = *(const float4*)(conv_b + tx * 8 + 4);
    float cb[8] = {cb0.x, cb0.y, cb0.z, cb0.w, cb1.x, cb1.y, cb1.z, cb1.w};
#pragma unroll
    for (int i = 0; i < 8; ++i) {
        float4 r0, r1;
        r0.x = fmaxf(acc[i][0] + cb[0], 0.f); r0.y = fmaxf(acc[i][1] + cb[1], 0.f);
        r0.z = fmaxf(acc[i][2] + cb[2], 0.f); r0.w = fmaxf(acc[i][3] + cb[3], 0.f);
        r1.x = fmaxf(acc[i][4] + cb[4], 0.f); r1.y = fmaxf(acc[i][5] + cb[5], 0.f);
        r1.z = fmaxf(acc[i][6] + cb[6], 0.f); r1.w = fmaxf(acc[i][7] + cb[7], 0.f);
        float* p = enc + (size_t)t * (Bdim * Ddim) + (ty * 8 + i) * 128 + tx * 8;
        *(float4*)p = r0;
        *(float4*)(p + 4) = r1;
    }
}

// ---------------- gi = enc @ W_ih^T + b_ih ----------------
__global__ __launch_bounds__(256) void k_gi(const float* __restrict__ enc,
                                            const float* __restrict__ Wt,   // [k][n] 128x384
                                            const float* __restrict__ b_ih,
                                            float* __restrict__ gi) {
    const int mt = blockIdx.x;   // t (128 rows)
    const int nt = blockIdx.y;   // 0..2
    __shared__ float As[128 * 64];
    __shared__ float Bs[64 * 128];
    const int tid = threadIdx.x;
    const int ty = tid >> 4, tx = tid & 15;

    float acc[8][8];
#pragma unroll
    for (int i = 0; i < 8; ++i)
#pragma unroll
        for (int j = 0; j < 8; ++j) acc[i][j] = 0.f;

    for (int kc = 0; kc < 128; kc += 64) {
        __syncthreads();
#pragma unroll
        for (int it = 0; it < 8; ++it) {
            int lin = tid + it * 256;
            int r = lin >> 4, k4 = lin & 15;
            float4 v = *(const float4*)(enc + (size_t)(mt * 128 + r) * 128 + kc + k4 * 4);
            int col = (k4 * 4 + ((r >> 3) << 2)) & 63;
            *(float4*)(As + r * 64 + col) = v;
        }
#pragma unroll
        for (int it = 0; it < 8; ++it) {
            int lin = tid + it * 256;
            int k = lin >> 5, d4 = lin & 31;
            float4 v = *(const float4*)(Wt + (size_t)(kc + k) * 384 + nt * 128 + d4 * 4);
            *(float4*)(Bs + k * 128 + d4 * 4) = v;
        }
        __syncthreads();

        for (int k = 0; k < 64; ++k) {
            float a[8], bb[8];
            const int acol = (k + 4 * ty) & 63;
#pragma unroll
            for (int i = 0; i < 8; ++i) a[i] = As[(ty * 8 + i) * 64 + acol];
            float4 b0 = *(const float4*)(Bs + k * 128 + tx * 8);
            float4 b1 = *(const float4*)(Bs + k * 128 + tx * 8 + 4);
            bb[0] = b0.x; bb[1] = b0.y; bb[2] = b0.z; bb[3] = b0.w;
            bb[4] = b1.x; bb[5] = b1.y; bb[6] = b1.z; bb[7] = b1.w;
#pragma unroll
            for (int i = 0; i < 8; ++i)
#pragma unroll
                for (int j = 0; j < 8; ++j) acc[i][j] = fmaf(a[i], bb[j], acc[i][j]);
        }
    }
    float4 bb0 = *(const float4*)(b_ih + nt * 128 + tx * 8);
    float4 bb1 = *(const float4*)(b_ih + nt * 128 + tx * 8 + 4);
    float bv[8] = {bb0.x, bb0.y, bb0.z, bb0.w, bb1.x, bb1.y, bb1.z, bb1.w};
#pragma unroll
    for (int i = 0; i < 8; ++i) {
        float4 r0, r1;
        r0.x = acc[i][0] + bv[0]; r0.y = acc[i][1] + bv[1];
        r0.z = acc[i][2] + bv[2]; r0.w = acc[i][3] + bv[3];
        r1.x = acc[i][4] + bv[4]; r1.y = acc[i][5] + bv[5];
        r1.z = acc[i][6] + bv[6]; r1.w = acc[i][7] + bv[7];
        float* p = gi + (size_t)(mt * 128 + ty * 8 + i) * 384 + nt * 128 + tx * 8;
        *(float4*)p = r0;
        *(float4*)(p + 4) = r1;
    }
}

// ---------------- GRU: one block per batch row, W_hh in registers ----------------
// thread (g = tid>>2, q = tid&3) holds W_hh rows {g, g+128, g+256}, k-quarter q*32..+32
__global__ __launch_bounds__(512) void k_gru(const float* __restrict__ gi,
                                             const float* __restrict__ Whh,
                                             const float* __restrict__ bhh,
                                             float* __restrict__ ctx,
                                             float* __restrict__ out_hidden) {
    const int b = blockIdx.x;
    const int tid = threadIdx.x;
    const int g = tid >> 2, q = tid & 3;
    __shared__ float hL[128];
    __shared__ float giL[2][384];

    float4 w0[8], w1[8], w2[8];
    {
        const float* W0 = Whh + (size_t)g * 128 + q * 32;
        const float* W1 = Whh + (size_t)(g + 128) * 128 + q * 32;
        const float* W2 = Whh + (size_t)(g + 256) * 128 + q * 32;
#pragma unroll
        for (int i = 0; i < 8; ++i) {
            w0[i] = *(const float4*)(W0 + i * 4);
            w1[i] = *(const float4*)(W1 + i * 4);
            w2[i] = *(const float4*)(W2 + i * 4);
        }
    }
    const float bh0 = bhh[g], bh1 = bhh[g + 128], bh2 = bhh[g + 256];

    if (tid < 128) hL[tid] = 0.f;
    if (tid < 96) {
        float4 v = *(const float4*)(gi + (size_t)b * 384 + tid * 4);
        *(float4*)(&giL[0][tid * 4]) = v;
    }
    __syncthreads();

    for (int t = 0; t < 256; ++t) {
        const int cur = t & 1;
        float4 h4[8];
#pragma unroll
        for (int i = 0; i < 8; ++i) h4[i] = *(const float4*)(&hL[q * 32 + i * 4]);
        const float hold = hL[g];
        const float ir = giL[cur][g], iz = giL[cur][g + 128], in = giL[cur][g + 256];

        float4 gpre = make_float4(0.f, 0.f, 0.f, 0.f);
        if (t < 255 && tid < 96)
            gpre = *(const float4*)(gi + ((size_t)(t + 1) * 128 + b) * 384 + tid * 4);

        float a0 = 0.f, a1 = 0.f, a2 = 0.f;
#pragma unroll
        for (int i = 0; i < 8; ++i) {
            a0 = fmaf(w0[i].x, h4[i].x, a0); a0 = fmaf(w0[i].y, h4[i].y, a0);
            a0 = fmaf(w0[i].z, h4[i].z, a0); a0 = fmaf(w0[i].w, h4[i].w, a0);
            a1 = fmaf(w1[i].x, h4[i].x, a1); a1 = fmaf(w1[i].y, h4[i].y, a1);
            a1 = fmaf(w1[i].z, h4[i].z, a1); a1 = fmaf(w1[i].w, h4[i].w, a1);
            a2 = fmaf(w2[i].x, h4[i].x, a2); a2 = fmaf(w2[i].y, h4[i].y, a2);
            a2 = fmaf(w2[i].z, h4[i].z, a2); a2 = fmaf(w2[i].w, h4[i].w, a2);
        }
        a0 += __shfl_xor(a0, 1); a0 += __shfl_xor(a0, 2);
        a1 += __shfl_xor(a1, 1); a1 += __shfl_xor(a1, 2);
        a2 += __shfl_xor(a2, 1); a2 += __shfl_xor(a2, 2);

        __syncthreads();   // all hL / giL[cur] reads complete

        // gates (all 4 lanes of a group compute identically; q==0 stores)
        float xr = ir + a0 + bh0;  xr = fminf(fmaxf(xr, -60.f), 60.f);
        float xz = iz + a1 + bh1;  xz = fminf(fmaxf(xz, -60.f), 60.f);
        float r = frcp(1.f + __expf(-xr));
        float z = frcp(1.f + __expf(-xz));
        float xn = in + r * (a2 + bh2); xn = fminf(fmaxf(xn, -15.f), 15.f);
        float e2 = __expf(-2.f * xn);
        float n = (1.f - e2) * frcp(1.f + e2);
        float hnew = (1.f - z) * n + z * hold;

        if (q == 0) {
            hL[g] = hnew;
            ctx[((size_t)t * 128 + b) * 128 + g] = hnew;
            if (t == 255) out_hidden[b * 128 + g] = hnew;
        }
        if (t < 255 && tid < 96) *(float4*)(&giL[cur ^ 1][tid * 4]) = gpre;
        __syncthreads();
    }
}

// ---------------- fused pred + scores + logsoftmax + diag + argmax ----------------
// block = (s, o). P[c][e] = ctx_s[s] @ pred_W[o]^T + pred_b ; Sc[b][c] = tgt @ P^T
__global__ __launch_bounds__(256) void k_cpc(const float* __restrict__ ctx,
                                             const float* __restrict__ enc,
                                             const float* __restrict__ pW,
                                             const float* __restrict__ pb,
                                             float* __restrict__ loss_part,
                                             float* __restrict__ corr_part) {
    const int s = blockIdx.x;   // 0..182
    const int o = blockIdx.y;   // 0..7
    __shared__ float As[128 * 128];   // rotated [r][(c + 4*(r>>3)) & 127]
    __shared__ float Bs[128 * 128];
    float* Lrow = Bs;                  // reuse after GEMM2
    float* red  = Bs + 128;
    const int tid = threadIdx.x;
    const int ty = tid >> 4, tx = tid & 15;

    // stage A = ctx[TI+s]  (c x d), rotated
    {
        const float* Ag = ctx + (size_t)(TIn + s) * (Bdim * Ddim);
        const float* Wg = pW + (size_t)o * (Ddim * Ddim);
#pragma unroll
        for (int it = 0; it < 16; ++it) {
            int lin = tid + it * 256;           // 0..4095
            int r = lin >> 5, c4 = lin & 31;
            int col = (c4 * 4 + ((r >> 3) << 2)) & 127;
            float4 va = *(const float4*)(Ag + (size_t)r * 128 + c4 * 4);
            *(float4*)(As + r * 128 + col) = va;
            float4 vb = *(const float4*)(Wg + (size_t)r * 128 + c4 * 4);
            *(float4*)(Bs + r * 128 + col) = vb;
        }
    }
    __syncthreads();

    // GEMM1: P[c][e] = sum_d A[c][d] * W[e][d]
    float acc[8][8];
#pragma unroll
    for (int i = 0; i < 8; ++i)
#pragma unroll
        for (int j = 0; j < 8; ++j) acc[i][j] = 0.f;
    for (int d = 0; d < 128; ++d) {
        float a[8], bb[8];
        const int ac = (d + 4 * ty) & 127;
        const int bc = (d + 4 * tx) & 127;
#pragma unroll
        for (int i = 0; i < 8; ++i) a[i] = As[(ty * 8 + i) * 128 + ac];
#pragma unroll
        for (int j = 0; j < 8; ++j) bb[j] = Bs[(tx * 8 + j) * 128 + bc];
#pragma unroll
        for (int i = 0; i < 8; ++i)
#pragma unroll
            for (int j = 0; j < 8; ++j) acc[i][j] = fmaf(a[i], bb[j], acc[i][j]);
    }
    __syncthreads();   // done reading As, Bs

    // write P (+bias) rotated into Bs; stage tgt = enc[TI+1+o+s] rotated into As
    {
        float4 p0 = *(const float4*)(pb + o * 128 + tx * 8);
        float4 p1 = *(const float4*)(pb + o * 128 + tx * 8 + 4);
        float pbv[8] = {p0.x, p0.y, p0.z, p0.w, p1.x, p1.y, p1.z, p1.w};
#pragma unroll
        for (int i = 0; i < 8; ++i) {
            float4 q0, q1;
            q0.x = acc[i][0] + pbv[0]; q0.y = acc[i][1] + pbv[1];
            q0.z = acc[i][2] + pbv[2]; q0.w = acc[i][3] + pbv[3];
            q1.x = acc[i][4] + pbv[4]; q1.y = acc[i][5] + pbv[5];
            q1.z = acc[i][6] + pbv[6]; q1.w = acc[i][7] + pbv[7];
            int row = ty * 8 + i;
            *(float4*)(Bs + row * 128 + ((tx * 8 + 4 * ty) & 127)) = q0;
            *(float4*)(Bs + row * 128 + ((tx * 8 + 4 + 4 * ty) & 127)) = q1;
        }
        const float* Tg = enc + (size_t)(TIn + 1 + o + s) * (Bdim * Ddim);
#pragma unroll
        for (int it = 0; it < 16; ++it) {
            int lin = tid + it * 256;
            int r = lin >> 5, c4 = lin & 31;
            int col = (c4 * 4 + ((r >> 3) << 2)) & 127;
            float4 v = *(const float4*)(Tg + (size_t)r * 128 + c4 * 4);
            *(float4*)(As + r * 128 + col) = v;
        }
    }
    __syncthreads();

    // GEMM2: Sc[b][c] = sum_e T[b][e] * P[c][e]
    float sc[8][8];
#pragma unroll
    for (int i = 0; i < 8; ++i)
#pragma unroll
        for (int j = 0; j < 8; ++j) sc[i][j] = 0.f;
    for (int e = 0; e < 128; ++e) {
        float a[8], bb[8];
        const int ac = (e + 4 * ty) & 127;
        const int bc = (e + 4 * tx) & 127;
#pragma unroll
        for (int i = 0; i < 8; ++i) a[i] = As[(ty * 8 + i) * 128 + ac];
#pragma unroll
        for (int j = 0; j < 8; ++j) bb[j] = Bs[(tx * 8 + j) * 128 + bc];
#pragma unroll
        for (int i = 0; i < 8; ++i)
#pragma unroll
            for (int j = 0; j < 8; ++j) sc[i][j] = fmaf(a[i], bb[j], sc[i][j]);
    }
    __syncthreads();

    // write Sc rotated into As (rows b, cols c)
#pragma unroll
    for (int i = 0; i < 8; ++i) {
        int row = ty * 8 + i;
        float4 q0, q1;
        q0.x = sc[i][0]; q0.y = sc[i][1]; q0.z = sc[i][2]; q0.w = sc[i][3];
        q1.x = sc[i][4]; q1.y = sc[i][5]; q1.z = sc[i][6]; q1.w = sc[i][7];
        *(float4*)(As + row * 128 + ((tx * 8 + 4 * ty) & 127)) = q0;
        *(float4*)(As + row * 128 + ((tx * 8 + 4 + 4 * ty) & 127)) = q1;
    }
    __syncthreads();

    // row softmax stats: Lrow[b] = max + log(sum exp)
    if (tid < 128) {
        const int row = tid;
        const int rot = (row >> 3) << 2;
        float m = NEG_INF;
        for (int c4 = 0; c4 < 32; ++c4) {
            float4 v = *(const float4*)(As + row * 128 + ((c4 * 4 + rot) & 127));
            m = fmaxf(m, fmaxf(fmaxf(v.x, v.y), fmaxf(v.z, v.w)));
        }
        float zz = 0.f;
        for (int c4 = 0; c4 < 32; ++c4) {
            float4 v = *(const float4*)(As + row * 128 + ((c4 * 4 + rot) & 127));
            zz += __expf(v.x - m) + __expf(v.y - m) + __expf(v.z - m) + __expf(v.w - m);
        }
        Lrow[row] = m + __logf(zz);
    }
    __syncthreads();

    // diag + column argmax
    float lsum = 0.f, csum = 0.f;
    if (tid < 128) {
        const int c = tid;
        lsum = As[c * 128 + ((c + ((c >> 3) << 2)) & 127)] - Lrow[c];
        float best = NEG_INF;
        int ab = 0;
        for (int bb2 = 0; bb2 < 128; ++bb2) {
            float v = As[bb2 * 128 + ((c + ((bb2 >> 3) << 2)) & 127)] - Lrow[bb2];
            if (v > best) { best = v; ab = bb2; }
        }
        csum = (ab == c) ? 1.f : 0.f;
    }
#pragma unroll
    for (int off = 32; off > 0; off >>= 1) {
        lsum += __shfl_down(lsum, off);
        csum += __shfl_down(csum, off);
    }
    const int wid = tid >> 6;
    if ((tid & 63) == 0) { red[wid] = lsum; red[4 + wid] = csum; }
    __syncthreads();
    if (tid == 0) {
        loss_part[o * Sn + s] = red[0] + red[1] + red[2] + red[3];
        corr_part[o * Sn + s] = red[4] + red[5] + red[6] + red[7];
    }
}

// ---------------- final reduction ----------------
__global__ __launch_bounds__(256) void k_final(const float* __restrict__ lp,
                                               const float* __restrict__ cp,
                                               float* __restrict__ out) {
    __shared__ float sl[256], sc2[256];
    const int tid = threadIdx.x;
    float l = 0.f, c = 0.f;
    for (int i = tid; i < TOn * Sn; i += 256) { l += lp[i]; c += cp[i]; }
    sl[tid] = l; sc2[tid] = c;
    __syncthreads();
    for (int s = 128; s > 0; s >>= 1) {
        if (tid < s) { sl[tid] += sl[tid + s]; sc2[tid] += sc2[tid + s]; }
        __syncthreads();
    }
    if (tid == 0) {
        out[0] = sc2[0] / DENOMF;      // accuracy
        out[1] = -sl[0] / DENOMF;      // loss
    }
}

extern "C" void kernel_launch(void* const* d_in, const int* in_sizes, int n_in,
                              void* d_out, int out_size, void* d_ws, size_t ws_size,
                              hipStream_t stream) {
    const float* X      = (const float*)d_in[0];
    const float* conv_w = (const float*)d_in[1];
    const float* conv_b = (const float*)d_in[2];
    const float* W_ih   = (const float*)d_in[3];
    const float* W_hh   = (const float*)d_in[4];
    const float* b_ih   = (const float*)d_in[5];
    const float* b_hh   = (const float*)d_in[6];
    const float* pred_W = (const float*)d_in[7];
    const float* pred_b = (const float*)d_in[8];
    float* out = (float*)d_out;
    float* ws  = (float*)d_ws;

    float* enc = ws + OFF_ENC;
    float* ctx = ws + OFF_CTX;
    float* gi  = ws + OFF_GI;
    float* Bc  = ws + OFF_BC;
    float* Wt  = ws + OFF_WT;
    float* lp  = ws + OFF_LP;
    float* cp  = ws + OFF_CP;

    k_prep <<<dim3(384),        dim3(256), 0, stream>>>(conv_w, Bc, W_ih, Wt);
    k_conv <<<dim3(256),        dim3(256), 0, stream>>>(X, Bc, conv_b, enc);
    k_gi   <<<dim3(256, 3),     dim3(256), 0, stream>>>(enc, Wt, b_ih, gi);
    k_gru  <<<dim3(128),        dim3(512), 0, stream>>>(gi, W_hh, b_hh, ctx, out + 2);
    k_cpc  <<<dim3(Sn, TOn),    dim3(256), 0, stream>>>(ctx, enc, pred_W, pred_b, lp, cp);
    k_final<<<dim3(1),          dim3(256), 0, stream>>>(lp, cp, out);
}

// Round 2
// 309.122 us; speedup vs baseline: 1.9823x; 1.9823x over previous
//
#include <hip/hip_runtime.h>
#include <math.h>

typedef __attribute__((ext_vector_type(8))) short bf16x8;
typedef __attribute__((ext_vector_type(4))) float f32x4;

#define Bdim 128
#define Cdim 12
#define Ddim 128
#define Tdim 256
#define TOn  8
#define TIn  64
#define Sn   183
#define DENOMF 187392.0f
#define NEG_INF -3.402823466e38f

// ---------------- workspace layout (bytes) ----------------
// enc_bf : 256*128*128*2 = 8388608
// ctx_bf : 8388608
// gi     : 256*128*384*4 = 50331648
// BcT    : 128*768*2     = 196608
// Wt     : 384*128*2     = 98304
// lp/cp  : 1464*4 each
#define OFFB_ENC 0
#define OFFB_CTX 8388608
#define OFFB_GI  16777216
#define OFFB_BCT 67108864
#define OFFB_WT  67305472
#define OFFB_LP  67403776
#define OFFB_CP  67409632

__device__ __forceinline__ float frcp(float x) { return __builtin_amdgcn_rcpf(x); }

__device__ __forceinline__ unsigned short f2b(float x) {
    unsigned int u = __builtin_bit_cast(unsigned int, x);
    u += 0x7FFFu + ((u >> 16) & 1u);
    return (unsigned short)(u >> 16);
}
__device__ __forceinline__ unsigned int pk2(float a, float b) {
    return (unsigned int)f2b(a) | ((unsigned int)f2b(b) << 16);
}

// ---------------- prep: weight transposes -> bf16 ----------------
__global__ __launch_bounds__(256) void k_prep(const float* __restrict__ conv_w,
                                              unsigned short* __restrict__ BcT,
                                              const float* __restrict__ W_ih,
                                              unsigned short* __restrict__ Wt) {
    int id = blockIdx.x * 256 + threadIdx.x;
    if (id < 128 * 768) {
        int d = id / 768, klin = id % 768;
        int kt = klin / 12, c = klin % 12;
        BcT[id] = f2b(conv_w[d * 768 + c * 64 + kt]);   // BcT[d][kt*12+c]
    }
    if (id < 384 * 128) Wt[id] = f2b(W_ih[id]);          // Wt[n][k]
}

// ---------------- conv as bf16 MFMA GEMM ----------------
// block t: enc[t][b][d] = relu( X[b][768t..768t+768] . BcT[d][:] + conv_b[d] )
__global__ __launch_bounds__(256) void k_conv(const float* __restrict__ X,
                                              const unsigned short* __restrict__ BcT,
                                              const float* __restrict__ conv_b,
                                              unsigned short* __restrict__ encb) {
    const int t = blockIdx.x;
    __shared__ __align__(16) char As[16384];   // [b=128][k=64] bf16, swizzled
    __shared__ __align__(16) char Bs[16384];   // [d=128][k=64] bf16, swizzled
    const int tid = threadIdx.x;
    const int lane = tid & 63, wid = tid >> 6;
    const int wy = wid >> 1, wx = wid & 1;
    const int g = lane >> 4, ln = lane & 15;

    f32x4 acc[4][4];
#pragma unroll
    for (int i = 0; i < 4; ++i)
#pragma unroll
        for (int j = 0; j < 4; ++j) acc[i][j] = (f32x4){0.f, 0.f, 0.f, 0.f};

    for (int kc = 0; kc < 768; kc += 64) {
        __syncthreads();
#pragma unroll
        for (int it = 0; it < 4; ++it) {
            int G = tid + it * 256;             // granule 0..1023 (16B each)
            int r = G >> 3, go = G & 7;
            const float* src = X + (size_t)r * (16384 * 12) + t * 768 + kc + go * 8;
            float4 f0 = *(const float4*)src;
            float4 f1 = *(const float4*)(src + 4);
            uint4 w; w.x = pk2(f0.x, f0.y); w.y = pk2(f0.z, f0.w);
            w.z = pk2(f1.x, f1.y); w.w = pk2(f1.z, f1.w);
            *(uint4*)(As + (r * 8 + (go ^ (r & 7))) * 16) = w;
            uint4 v = *(const uint4*)(BcT + (size_t)r * 768 + kc + go * 8);
            *(uint4*)(Bs + (r * 8 + (go ^ (r & 7))) * 16) = v;
        }
        __syncthreads();
#pragma unroll
        for (int ks = 0; ks < 2; ++ks) {
            bf16x8 af[4], bfr[4];
            const int kb = ks * 64 + g * 16;
#pragma unroll
            for (int mi = 0; mi < 4; ++mi) {
                int r = wy * 64 + mi * 16 + ln;
                af[mi] = *(const bf16x8*)(As + r * 128 + (kb ^ ((r & 7) << 4)));
            }
#pragma unroll
            for (int ni = 0; ni < 4; ++ni) {
                int r = wx * 64 + ni * 16 + ln;
                bfr[ni] = *(const bf16x8*)(Bs + r * 128 + (kb ^ ((r & 7) << 4)));
            }
#pragma unroll
            for (int mi = 0; mi < 4; ++mi)
#pragma unroll
                for (int ni = 0; ni < 4; ++ni)
                    acc[mi][ni] = __builtin_amdgcn_mfma_f32_16x16x32_bf16(af[mi], bfr[ni], acc[mi][ni], 0, 0, 0);
        }
    }
    float cb[4];
#pragma unroll
    for (int ni = 0; ni < 4; ++ni) cb[ni] = conv_b[wx * 64 + ni * 16 + ln];
    unsigned short* dst = encb + (size_t)t * (128 * 128);
#pragma unroll
    for (int mi = 0; mi < 4; ++mi)
#pragma unroll
        for (int jj = 0; jj < 4; ++jj) {
            int b = wy * 64 + mi * 16 + g * 4 + jj;
#pragma unroll
            for (int ni = 0; ni < 4; ++ni) {
                int d = wx * 64 + ni * 16 + ln;
                dst[b * 128 + d] = f2b(fmaxf(acc[mi][ni][jj] + cb[ni], 0.f));
            }
        }
}

// ---------------- gi = enc @ W_ih^T + b_ih  (bf16 MFMA, fp32 out) ----------------
__global__ __launch_bounds__(256) void k_gi(const unsigned short* __restrict__ encb,
                                            const unsigned short* __restrict__ Wt,
                                            const float* __restrict__ b_ih,
                                            float* __restrict__ gi) {
    const int mt = blockIdx.x, nt = blockIdx.y;
    __shared__ __align__(16) char As[32768];   // [m=128][k=128]
    __shared__ __align__(16) char Bs[32768];   // [n=128][k=128]
    const int tid = threadIdx.x;
    const int lane = tid & 63, wid = tid >> 6;
    const int wy = wid >> 1, wx = wid & 1;
    const int g = lane >> 4, ln = lane & 15;

    {
        const unsigned short* asrc = encb + (size_t)mt * (128 * 128);
        const unsigned short* bsrc = Wt + (size_t)nt * (128 * 128);
#pragma unroll
        for (int it = 0; it < 8; ++it) {
            int G = tid + it * 256;             // granule 0..2047
            int r = G >> 4, go = G & 15;
            *(uint4*)(As + (r * 16 + (go ^ (r & 7))) * 16) = *(const uint4*)(asrc + r * 128 + go * 8);
            *(uint4*)(Bs + (r * 16 + (go ^ (r & 7))) * 16) = *(const uint4*)(bsrc + r * 128 + go * 8);
        }
    }
    __syncthreads();

    f32x4 acc[4][4];
#pragma unroll
    for (int i = 0; i < 4; ++i)
#pragma unroll
        for (int j = 0; j < 4; ++j) acc[i][j] = (f32x4){0.f, 0.f, 0.f, 0.f};
#pragma unroll
    for (int ks = 0; ks < 4; ++ks) {
        bf16x8 af[4], bfr[4];
        const int kb = ks * 64 + g * 16;
#pragma unroll
        for (int mi = 0; mi < 4; ++mi) {
            int r = wy * 64 + mi * 16 + ln;
            af[mi] = *(const bf16x8*)(As + r * 256 + (kb ^ ((r & 7) << 4)));
        }
#pragma unroll
        for (int ni = 0; ni < 4; ++ni) {
            int r = wx * 64 + ni * 16 + ln;
            bfr[ni] = *(const bf16x8*)(Bs + r * 256 + (kb ^ ((r & 7) << 4)));
        }
#pragma unroll
        for (int mi = 0; mi < 4; ++mi)
#pragma unroll
            for (int ni = 0; ni < 4; ++ni)
                acc[mi][ni] = __builtin_amdgcn_mfma_f32_16x16x32_bf16(af[mi], bfr[ni], acc[mi][ni], 0, 0, 0);
    }
    float bv[4];
#pragma unroll
    for (int ni = 0; ni < 4; ++ni) bv[ni] = b_ih[nt * 128 + wx * 64 + ni * 16 + ln];
#pragma unroll
    for (int mi = 0; mi < 4; ++mi)
#pragma unroll
        for (int jj = 0; jj < 4; ++jj) {
            int m = mt * 128 + wy * 64 + mi * 16 + g * 4 + jj;
#pragma unroll
            for (int ni = 0; ni < 4; ++ni) {
                int n = nt * 128 + wx * 64 + ni * 16 + ln;
                gi[(size_t)m * 384 + n] = acc[mi][ni][jj] + bv[ni];
            }
        }
}

// ---------------- GRU: one block per batch row, W_hh in registers (fp32) ----------------
__global__ __launch_bounds__(512) void k_gru(const float* __restrict__ gi,
                                             const float* __restrict__ Whh,
                                             const float* __restrict__ bhh,
                                             unsigned short* __restrict__ ctxb,
                                             float* __restrict__ out_hidden) {
    const int b = blockIdx.x;
    const int tid = threadIdx.x;
    const int g = tid >> 2, q = tid & 3;
    __shared__ float hL[128];
    __shared__ float giL[2][384];

    float4 w0[8], w1[8], w2[8];
    {
        const float* W0 = Whh + (size_t)g * 128 + q * 32;
        const float* W1 = Whh + (size_t)(g + 128) * 128 + q * 32;
        const float* W2 = Whh + (size_t)(g + 256) * 128 + q * 32;
#pragma unroll
        for (int i = 0; i < 8; ++i) {
            w0[i] = *(const float4*)(W0 + i * 4);
            w1[i] = *(const float4*)(W1 + i * 4);
            w2[i] = *(const float4*)(W2 + i * 4);
        }
    }
    const float bh0 = bhh[g], bh1 = bhh[g + 128], bh2 = bhh[g + 256];

    if (tid < 128) hL[tid] = 0.f;
    if (tid < 96) {
        float4 v = *(const float4*)(gi + (size_t)b * 384 + tid * 4);
        *(float4*)(&giL[0][tid * 4]) = v;
    }
    __syncthreads();

    for (int t = 0; t < 256; ++t) {
        const int cur = t & 1;
        float4 h4[8];
#pragma unroll
        for (int i = 0; i < 8; ++i) h4[i] = *(const float4*)(&hL[q * 32 + i * 4]);
        const float hold = hL[g];
        const float ir = giL[cur][g], iz = giL[cur][g + 128], in = giL[cur][g + 256];

        float4 gpre = make_float4(0.f, 0.f, 0.f, 0.f);
        if (t < 255 && tid < 96)
            gpre = *(const float4*)(gi + ((size_t)(t + 1) * 128 + b) * 384 + tid * 4);

        float a0 = 0.f, a1 = 0.f, a2 = 0.f;
#pragma unroll
        for (int i = 0; i < 8; ++i) {
            a0 = fmaf(w0[i].x, h4[i].x, a0); a0 = fmaf(w0[i].y, h4[i].y, a0);
            a0 = fmaf(w0[i].z, h4[i].z, a0); a0 = fmaf(w0[i].w, h4[i].w, a0);
            a1 = fmaf(w1[i].x, h4[i].x, a1); a1 = fmaf(w1[i].y, h4[i].y, a1);
            a1 = fmaf(w1[i].z, h4[i].z, a1); a1 = fmaf(w1[i].w, h4[i].w, a1);
            a2 = fmaf(w2[i].x, h4[i].x, a2); a2 = fmaf(w2[i].y, h4[i].y, a2);
            a2 = fmaf(w2[i].z, h4[i].z, a2); a2 = fmaf(w2[i].w, h4[i].w, a2);
        }
        a0 += __shfl_xor(a0, 1); a0 += __shfl_xor(a0, 2);
        a1 += __shfl_xor(a1, 1); a1 += __shfl_xor(a1, 2);
        a2 += __shfl_xor(a2, 1); a2 += __shfl_xor(a2, 2);

        __syncthreads();

        float xr = ir + a0 + bh0;  xr = fminf(fmaxf(xr, -60.f), 60.f);
        float xz = iz + a1 + bh1;  xz = fminf(fmaxf(xz, -60.f), 60.f);
        float r = frcp(1.f + __expf(-xr));
        float z = frcp(1.f + __expf(-xz));
        float xn = in + r * (a2 + bh2); xn = fminf(fmaxf(xn, -15.f), 15.f);
        float e2 = __expf(-2.f * xn);
        float n = (1.f - e2) * frcp(1.f + e2);
        float hnew = (1.f - z) * n + z * hold;

        if (q == 0) {
            hL[g] = hnew;
            ctxb[((size_t)t * 128 + b) * 128 + g] = f2b(hnew);
            if (t == 255) out_hidden[b * 128 + g] = hnew;
        }
        if (t < 255 && tid < 96) *(float4*)(&giL[cur ^ 1][tid * 4]) = gpre;
        __syncthreads();
    }
}

// ---------------- fused CPC: MFMA GEMM1 (P^T) -> MFMA GEMM2 (Sc) -> reg softmax ----------------
__global__ __launch_bounds__(256) void k_cpc(const unsigned short* __restrict__ ctxb,
                                             const unsigned short* __restrict__ encb,
                                             const float* __restrict__ pW,
                                             const float* __restrict__ pb,
                                             float* __restrict__ lp,
                                             float* __restrict__ cp) {
    const int s = blockIdx.x, o = blockIdx.y;
    __shared__ __align__(16) char bufA[32768];   // ctx [c][d] -> later tgt [b][e]
    __shared__ __align__(16) char bufB[32768];   // Wo  [e][d] -> later P   [c][e]
    __shared__ float rowm[2][128], rowsum[2][128];
    __shared__ float Lrow[128], diagv[128];
    __shared__ float colv[2][128];
    __shared__ int   colix[2][128];
    __shared__ float fin[4];

    const int tid = threadIdx.x;
    const int lane = tid & 63, wid = tid >> 6;
    const int wy = wid >> 1, wx = wid & 1;
    const int g = lane >> 4, ln = lane & 15;

    // stage ctx -> bufA (bf16 copy), Wo fp32->bf16 -> bufB (both swizzled)
    {
        const unsigned short* src = ctxb + (size_t)(TIn + s) * (128 * 128);
        const float* wsrc = pW + (size_t)o * (128 * 128);
#pragma unroll
        for (int it = 0; it < 8; ++it) {
            int G = tid + it * 256;
            int r = G >> 4, go = G & 15;
            *(uint4*)(bufA + (r * 16 + (go ^ (r & 7))) * 16) = *(const uint4*)(src + r * 128 + go * 8);
            float4 f0 = *(const float4*)(wsrc + r * 128 + go * 8);
            float4 f1 = *(const float4*)(wsrc + r * 128 + go * 8 + 4);
            uint4 w; w.x = pk2(f0.x, f0.y); w.y = pk2(f0.z, f0.w);
            w.z = pk2(f1.x, f1.y); w.w = pk2(f1.z, f1.w);
            *(uint4*)(bufB + (r * 16 + (go ^ (r & 7))) * 16) = w;
        }
    }
    __syncthreads();

    // GEMM1: P^T[e][c] = Wo[e][:] . ctx[c][:]
    f32x4 acc[4][4];
#pragma unroll
    for (int i = 0; i < 4; ++i)
#pragma unroll
        for (int j = 0; j < 4; ++j) acc[i][j] = (f32x4){0.f, 0.f, 0.f, 0.f};
#pragma unroll
    for (int ks = 0; ks < 4; ++ks) {
        bf16x8 af[4], bfr[4];
        const int kb = ks * 64 + g * 16;
#pragma unroll
        for (int mi = 0; mi < 4; ++mi) {
            int r = wy * 64 + mi * 16 + ln;
            af[mi] = *(const bf16x8*)(bufB + r * 256 + (kb ^ ((r & 7) << 4)));
        }
#pragma unroll
        for (int ni = 0; ni < 4; ++ni) {
            int r = wx * 64 + ni * 16 + ln;
            bfr[ni] = *(const bf16x8*)(bufA + r * 256 + (kb ^ ((r & 7) << 4)));
        }
#pragma unroll
        for (int mi = 0; mi < 4; ++mi)
#pragma unroll
            for (int ni = 0; ni < 4; ++ni)
                acc[mi][ni] = __builtin_amdgcn_mfma_f32_16x16x32_bf16(af[mi], bfr[ni], acc[mi][ni], 0, 0, 0);
    }
    __syncthreads();   // all frag reads of bufA/bufB done

    // write P[c][e] (bias added, bf16, swizzled) into bufB; stage tgt into bufA
    {
        float pbv[4][4];
#pragma unroll
        for (int mi = 0; mi < 4; ++mi) {
            int e0 = wy * 64 + mi * 16 + g * 4;
#pragma unroll
            for (int jj = 0; jj < 4; ++jj) pbv[mi][jj] = pb[o * 128 + e0 + jj];
        }
#pragma unroll
        for (int mi = 0; mi < 4; ++mi) {
            int e0 = wy * 64 + mi * 16 + g * 4;
#pragma unroll
            for (int ni = 0; ni < 4; ++ni) {
                int c = wx * 64 + ni * 16 + ln;
                unsigned int lo = pk2(acc[mi][ni][0] + pbv[mi][0], acc[mi][ni][1] + pbv[mi][1]);
                unsigned int hi = pk2(acc[mi][ni][2] + pbv[mi][2], acc[mi][ni][3] + pbv[mi][3]);
                int byteoff = c * 256 + ((e0 * 2) ^ ((c & 7) << 4));
                *(uint2*)(bufB + byteoff) = make_uint2(lo, hi);
            }
        }
        const unsigned short* tsrc = encb + (size_t)(TIn + 1 + o + s) * (128 * 128);
#pragma unroll
        for (int it = 0; it < 8; ++it) {
            int G = tid + it * 256;
            int r = G >> 4, go = G & 15;
            *(uint4*)(bufA + (r * 16 + (go ^ (r & 7))) * 16) = *(const uint4*)(tsrc + r * 128 + go * 8);
        }
    }
    __syncthreads();

    // GEMM2: Sc[b][c] = tgt[b][:] . P[c][:]
#pragma unroll
    for (int i = 0; i < 4; ++i)
#pragma unroll
        for (int j = 0; j < 4; ++j) acc[i][j] = (f32x4){0.f, 0.f, 0.f, 0.f};
#pragma unroll
    for (int ks = 0; ks < 4; ++ks) {
        bf16x8 af[4], bfr[4];
        const int kb = ks * 64 + g * 16;
#pragma unroll
        for (int mi = 0; mi < 4; ++mi) {
            int r = wy * 64 + mi * 16 + ln;
            af[mi] = *(const bf16x8*)(bufA + r * 256 + (kb ^ ((r & 7) << 4)));
        }
#pragma unroll
        for (int ni = 0; ni < 4; ++ni) {
            int r = wx * 64 + ni * 16 + ln;
            bfr[ni] = *(const bf16x8*)(bufB + r * 256 + (kb ^ ((r & 7) << 4)));
        }
#pragma unroll
        for (int mi = 0; mi < 4; ++mi)
#pragma unroll
            for (int ni = 0; ni < 4; ++ni)
                acc[mi][ni] = __builtin_amdgcn_mfma_f32_16x16x32_bf16(af[mi], bfr[ni], acc[mi][ni], 0, 0, 0);
    }

    // row stats (softmax over c, per row b) + diag extraction, all in-register
#pragma unroll
    for (int mi = 0; mi < 4; ++mi) {
#pragma unroll
        for (int jj = 0; jj < 4; ++jj) {
            float m = fmaxf(fmaxf(acc[mi][0][jj], acc[mi][1][jj]),
                            fmaxf(acc[mi][2][jj], acc[mi][3][jj]));
            m = fmaxf(m, __shfl_xor(m, 1)); m = fmaxf(m, __shfl_xor(m, 2));
            m = fmaxf(m, __shfl_xor(m, 4)); m = fmaxf(m, __shfl_xor(m, 8));
            float sm = __expf(acc[mi][0][jj] - m) + __expf(acc[mi][1][jj] - m)
                     + __expf(acc[mi][2][jj] - m) + __expf(acc[mi][3][jj] - m);
            sm += __shfl_xor(sm, 1); sm += __shfl_xor(sm, 2);
            sm += __shfl_xor(sm, 4); sm += __shfl_xor(sm, 8);
            int b = wy * 64 + mi * 16 + g * 4 + jj;
            if (ln == 0) { rowm[wx][b] = m; rowsum[wx][b] = sm; }
            if (wy == wx && ln == g * 4 + jj) diagv[b] = acc[mi][mi][jj];
        }
    }
    __syncthreads();
    if (tid < 128) {
        float m0 = rowm[0][tid], m1 = rowm[1][tid];
        float mm = fmaxf(m0, m1);
        float ss = rowsum[0][tid] * __expf(m0 - mm) + rowsum[1][tid] * __expf(m1 - mm);
        Lrow[tid] = mm + __logf(ss);
    }
    __syncthreads();

    // column argmax of (Sc[b][c] - Lrow[b]) over b
    float Lr[4][4];
#pragma unroll
    for (int mi = 0; mi < 4; ++mi)
#pragma unroll
        for (int jj = 0; jj < 4; ++jj) Lr[mi][jj] = Lrow[wy * 64 + mi * 16 + g * 4 + jj];

#pragma unroll
    for (int ni = 0; ni < 4; ++ni) {
        float best = NEG_INF; int bidx = 0x7fffffff;
#pragma unroll
        for (int mi = 0; mi < 4; ++mi)
#pragma unroll
            for (int jj = 0; jj < 4; ++jj) {
                float v = acc[mi][ni][jj] - Lr[mi][jj];
                int r = wy * 64 + mi * 16 + g * 4 + jj;
                if (v > best) { best = v; bidx = r; }
            }
#pragma unroll
        for (int mask = 16; mask <= 32; mask <<= 1) {
            float ov = __shfl_xor(best, mask);
            int   oi = __shfl_xor(bidx, mask);
            if (ov > best || (ov == best && oi < bidx)) { best = ov; bidx = oi; }
        }
        if (g == 0) {
            int c = wx * 64 + ni * 16 + ln;
            colv[wy][c] = best; colix[wy][c] = bidx;
        }
    }
    __syncthreads();

    float lsum = 0.f, csum = 0.f;
    if (tid < 128) {
        lsum = diagv[tid] - Lrow[tid];
        float v0 = colv[0][tid], v1 = colv[1][tid];
        int ix = (v1 > v0) ? colix[1][tid] : colix[0][tid];   // tie -> lower row (colix[0])
        csum = (ix == tid) ? 1.f : 0.f;
    }
#pragma unroll
    for (int off = 32; off > 0; off >>= 1) {
        lsum += __shfl_down(lsum, off);
        csum += __shfl_down(csum, off);
    }
    if (lane == 0 && wid < 2) { fin[wid] = lsum; fin[2 + wid] = csum; }
    __syncthreads();
    if (tid == 0) {
        lp[o * Sn + s] = fin[0] + fin[1];
        cp[o * Sn + s] = fin[2] + fin[3];
    }
}

// ---------------- final reduction ----------------
__global__ __launch_bounds__(256) void k_final(const float* __restrict__ lp,
                                               const float* __restrict__ cp,
                                               float* __restrict__ out) {
    __shared__ float sl[256], sc2[256];
    const int tid = threadIdx.x;
    float l = 0.f, c = 0.f;
    for (int i = tid; i < TOn * Sn; i += 256) { l += lp[i]; c += cp[i]; }
    sl[tid] = l; sc2[tid] = c;
    __syncthreads();
    for (int s = 128; s > 0; s >>= 1) {
        if (tid < s) { sl[tid] += sl[tid + s]; sc2[tid] += sc2[tid + s]; }
        __syncthreads();
    }
    if (tid == 0) {
        out[0] = sc2[0] / DENOMF;      // accuracy
        out[1] = -sl[0] / DENOMF;      // loss
    }
}

extern "C" void kernel_launch(void* const* d_in, const int* in_sizes, int n_in,
                              void* d_out, int out_size, void* d_ws, size_t ws_size,
                              hipStream_t stream) {
    const float* X      = (const float*)d_in[0];
    const float* conv_w = (const float*)d_in[1];
    const float* conv_b = (const float*)d_in[2];
    const float* W_ih   = (const float*)d_in[3];
    const float* W_hh   = (const float*)d_in[4];
    const float* b_ih   = (const float*)d_in[5];
    const float* b_hh   = (const float*)d_in[6];
    const float* pred_W = (const float*)d_in[7];
    const float* pred_b = (const float*)d_in[8];
    float* out = (float*)d_out;
    char*  ws  = (char*)d_ws;

    unsigned short* encb = (unsigned short*)(ws + OFFB_ENC);
    unsigned short* ctxb = (unsigned short*)(ws + OFFB_CTX);
    float*          gi   = (float*)(ws + OFFB_GI);
    unsigned short* BcT  = (unsigned short*)(ws + OFFB_BCT);
    unsigned short* Wt   = (unsigned short*)(ws + OFFB_WT);
    float*          lp   = (float*)(ws + OFFB_LP);
    float*          cp   = (float*)(ws + OFFB_CP);

    k_prep <<<dim3(384),     dim3(256), 0, stream>>>(conv_w, BcT, W_ih, Wt);
    k_conv <<<dim3(256),     dim3(256), 0, stream>>>(X, BcT, conv_b, encb);
    k_gi   <<<dim3(256, 3),  dim3(256), 0, stream>>>(encb, Wt, b_ih, gi);
    k_gru  <<<dim3(128),     dim3(512), 0, stream>>>(gi, W_hh, b_hh, ctxb, out + 2);
    k_cpc  <<<dim3(Sn, TOn), dim3(256), 0, stream>>>(ctxb, encb, pred_W, pred_b, lp, cp);
    k_final<<<dim3(1),       dim3(256), 0, stream>>>(lp, cp, out);
}

// Round 3
// 274.339 us; speedup vs baseline: 2.2337x; 1.1268x over previous
//
#include <hip/hip_runtime.h>
#include <math.h>

typedef __attribute__((ext_vector_type(8))) short bf16x8;
typedef __attribute__((ext_vector_type(4))) float f32x4;

#define Bdim 128
#define Cdim 12
#define Ddim 128
#define Tdim 256
#define TOn  8
#define TIn  64
#define Sn   183
#define DENOMF 187392.0f
#define NEG_INF -3.402823466e38f

// ---------------- workspace layout (bytes) ----------------
#define OFFB_ENC 0
#define OFFB_CTX 8388608
#define OFFB_GI  16777216
#define OFFB_BCT 67108864
#define OFFB_WT  67305472
#define OFFB_LP  67403776
#define OFFB_CP  67409632

__device__ __forceinline__ float frcp(float x) { return __builtin_amdgcn_rcpf(x); }

__device__ __forceinline__ unsigned short f2b(float x) {
    unsigned int u = __builtin_bit_cast(unsigned int, x);
    u += 0x7FFFu + ((u >> 16) & 1u);
    return (unsigned short)(u >> 16);
}
__device__ __forceinline__ unsigned int pk2(float a, float b) {
    return (unsigned int)f2b(a) | ((unsigned int)f2b(b) << 16);
}

// ---------------- prep: weight transposes -> bf16 ----------------
__global__ __launch_bounds__(256) void k_prep(const float* __restrict__ conv_w,
                                              unsigned short* __restrict__ BcT,
                                              const float* __restrict__ W_ih,
                                              unsigned short* __restrict__ Wt) {
    int id = blockIdx.x * 256 + threadIdx.x;
    if (id < 128 * 768) {
        int d = id / 768, klin = id % 768;
        int kt = klin / 12, c = klin % 12;
        BcT[id] = f2b(conv_w[d * 768 + c * 64 + kt]);   // BcT[d][kt*12+c]
    }
    if (id < 384 * 128) Wt[id] = f2b(W_ih[id]);          // Wt[n][k]
}

// ---------------- conv as bf16 MFMA GEMM ----------------
__global__ __launch_bounds__(256) void k_conv(const float* __restrict__ X,
                                              const unsigned short* __restrict__ BcT,
                                              const float* __restrict__ conv_b,
                                              unsigned short* __restrict__ encb) {
    const int t = blockIdx.x;
    __shared__ __align__(16) char As[16384];   // [b=128][k=64] bf16, swizzled
    __shared__ __align__(16) char Bs[16384];   // [d=128][k=64] bf16, swizzled
    const int tid = threadIdx.x;
    const int lane = tid & 63, wid = tid >> 6;
    const int wy = wid >> 1, wx = wid & 1;
    const int g = lane >> 4, ln = lane & 15;

    f32x4 acc[4][4];
#pragma unroll
    for (int i = 0; i < 4; ++i)
#pragma unroll
        for (int j = 0; j < 4; ++j) acc[i][j] = (f32x4){0.f, 0.f, 0.f, 0.f};

    for (int kc = 0; kc < 768; kc += 64) {
        __syncthreads();
#pragma unroll
        for (int it = 0; it < 4; ++it) {
            int G = tid + it * 256;             // granule 0..1023 (16B each)
            int r = G >> 3, go = G & 7;
            const float* src = X + (size_t)r * (16384 * 12) + t * 768 + kc + go * 8;
            float4 f0 = *(const float4*)src;
            float4 f1 = *(const float4*)(src + 4);
            uint4 w; w.x = pk2(f0.x, f0.y); w.y = pk2(f0.z, f0.w);
            w.z = pk2(f1.x, f1.y); w.w = pk2(f1.z, f1.w);
            *(uint4*)(As + (r * 8 + (go ^ (r & 7))) * 16) = w;
            uint4 v = *(const uint4*)(BcT + (size_t)r * 768 + kc + go * 8);
            *(uint4*)(Bs + (r * 8 + (go ^ (r & 7))) * 16) = v;
        }
        __syncthreads();
#pragma unroll
        for (int ks = 0; ks < 2; ++ks) {
            bf16x8 af[4], bfr[4];
            const int kb = ks * 64 + g * 16;
#pragma unroll
            for (int mi = 0; mi < 4; ++mi) {
                int r = wy * 64 + mi * 16 + ln;
                af[mi] = *(const bf16x8*)(As + r * 128 + (kb ^ ((r & 7) << 4)));
            }
#pragma unroll
            for (int ni = 0; ni < 4; ++ni) {
                int r = wx * 64 + ni * 16 + ln;
                bfr[ni] = *(const bf16x8*)(Bs + r * 128 + (kb ^ ((r & 7) << 4)));
            }
#pragma unroll
            for (int mi = 0; mi < 4; ++mi)
#pragma unroll
                for (int ni = 0; ni < 4; ++ni)
                    acc[mi][ni] = __builtin_amdgcn_mfma_f32_16x16x32_bf16(af[mi], bfr[ni], acc[mi][ni], 0, 0, 0);
        }
    }
    float cb[4];
#pragma unroll
    for (int ni = 0; ni < 4; ++ni) cb[ni] = conv_b[wx * 64 + ni * 16 + ln];
    unsigned short* dst = encb + (size_t)t * (128 * 128);
#pragma unroll
    for (int mi = 0; mi < 4; ++mi)
#pragma unroll
        for (int jj = 0; jj < 4; ++jj) {
            int b = wy * 64 + mi * 16 + g * 4 + jj;
#pragma unroll
            for (int ni = 0; ni < 4; ++ni) {
                int d = wx * 64 + ni * 16 + ln;
                dst[b * 128 + d] = f2b(fmaxf(acc[mi][ni][jj] + cb[ni], 0.f));
            }
        }
}

// ---------------- gi = enc @ W_ih^T + b_ih  (bf16 MFMA, fp32 out) ----------------
__global__ __launch_bounds__(256) void k_gi(const unsigned short* __restrict__ encb,
                                            const unsigned short* __restrict__ Wt,
                                            const float* __restrict__ b_ih,
                                            float* __restrict__ gi) {
    const int mt = blockIdx.x, nt = blockIdx.y;
    __shared__ __align__(16) char As[32768];   // [m=128][k=128]
    __shared__ __align__(16) char Bs[32768];   // [n=128][k=128]
    const int tid = threadIdx.x;
    const int lane = tid & 63, wid = tid >> 6;
    const int wy = wid >> 1, wx = wid & 1;
    const int g = lane >> 4, ln = lane & 15;

    {
        const unsigned short* asrc = encb + (size_t)mt * (128 * 128);
        const unsigned short* bsrc = Wt + (size_t)nt * (128 * 128);
#pragma unroll
        for (int it = 0; it < 8; ++it) {
            int G = tid + it * 256;             // granule 0..2047
            int r = G >> 4, go = G & 15;
            *(uint4*)(As + (r * 16 + (go ^ (r & 7))) * 16) = *(const uint4*)(asrc + r * 128 + go * 8);
            *(uint4*)(Bs + (r * 16 + (go ^ (r & 7))) * 16) = *(const uint4*)(bsrc + r * 128 + go * 8);
        }
    }
    __syncthreads();

    f32x4 acc[4][4];
#pragma unroll
    for (int i = 0; i < 4; ++i)
#pragma unroll
        for (int j = 0; j < 4; ++j) acc[i][j] = (f32x4){0.f, 0.f, 0.f, 0.f};
#pragma unroll
    for (int ks = 0; ks < 4; ++ks) {
        bf16x8 af[4], bfr[4];
        const int kb = ks * 64 + g * 16;
#pragma unroll
        for (int mi = 0; mi < 4; ++mi) {
            int r = wy * 64 + mi * 16 + ln;
            af[mi] = *(const bf16x8*)(As + r * 256 + (kb ^ ((r & 7) << 4)));
        }
#pragma unroll
        for (int ni = 0; ni < 4; ++ni) {
            int r = wx * 64 + ni * 16 + ln;
            bfr[ni] = *(const bf16x8*)(Bs + r * 256 + (kb ^ ((r & 7) << 4)));
        }
#pragma unroll
        for (int mi = 0; mi < 4; ++mi)
#pragma unroll
            for (int ni = 0; ni < 4; ++ni)
                acc[mi][ni] = __builtin_amdgcn_mfma_f32_16x16x32_bf16(af[mi], bfr[ni], acc[mi][ni], 0, 0, 0);
    }
    float bv[4];
#pragma unroll
    for (int ni = 0; ni < 4; ++ni) bv[ni] = b_ih[nt * 128 + wx * 64 + ni * 16 + ln];
#pragma unroll
    for (int mi = 0; mi < 4; ++mi)
#pragma unroll
        for (int jj = 0; jj < 4; ++jj) {
            int m = mt * 128 + wy * 64 + mi * 16 + g * 4 + jj;
#pragma unroll
            for (int ni = 0; ni < 4; ++ni) {
                int n = nt * 128 + wx * 64 + ni * 16 + ln;
                gi[(size_t)m * 384 + n] = acc[mi][ni][jj] + bv[ni];
            }
        }
}

// ---------------- GRU v2: W_hh register-resident (VGPR cap raised), 1 barrier/step,
//                  conflict-free rotated h copies, depth-2 gi prefetch ----------------
// thread (g = tid>>2, q = tid&3): W_hh rows {g, g+128, g+256}, k-quarter q*32..+32
__global__ __launch_bounds__(512, 2) void k_gru(const float* __restrict__ gi,
                                                const float* __restrict__ Whh,
                                                const float* __restrict__ bhh,
                                                unsigned short* __restrict__ ctxb,
                                                float* __restrict__ out_hidden) {
    const int b = blockIdx.x;
    const int tid = threadIdx.x;
    const int g = tid >> 2, q = tid & 3;
    // copy q lives at word base (buf*4+q)*136; 136%32==8 -> copy q banks offset 8q
    __shared__ float hbuf[2][4][136];

    float4 w0[8], w1[8], w2[8];
    {
        const float* W0 = Whh + (size_t)g * 128 + q * 32;
        const float* W1 = Whh + (size_t)(g + 128) * 128 + q * 32;
        const float* W2 = Whh + (size_t)(g + 256) * 128 + q * 32;
#pragma unroll
        for (int i = 0; i < 8; ++i) {
            w0[i] = *(const float4*)(W0 + i * 4);
            w1[i] = *(const float4*)(W1 + i * 4);
            w2[i] = *(const float4*)(W2 + i * 4);
        }
    }
    const float bh0 = bhh[g], bh1 = bhh[g + 128], bh2 = bhh[g + 256];

    hbuf[0][q][g] = 0.f;

    // depth-2 prefetch of gate pre-activations
    float p0r = gi[(size_t)b * 384 + g];
    float p0z = gi[(size_t)b * 384 + 128 + g];
    float p0n = gi[(size_t)b * 384 + 256 + g];
    float p1r = gi[((size_t)128 + b) * 384 + g];
    float p1z = gi[((size_t)128 + b) * 384 + 128 + g];
    float p1n = gi[((size_t)128 + b) * 384 + 256 + g];
    __syncthreads();

    for (int t = 0; t < 256; ++t) {
        const int cur = t & 1;
        // issue prefetch for t+2 first (longest latency)
        float p2r = 0.f, p2z = 0.f, p2n = 0.f;
        if (t + 2 < 256) {
            const float* gp = gi + ((size_t)(t + 2) * 128 + b) * 384;
            p2r = gp[g]; p2z = gp[128 + g]; p2n = gp[256 + g];
        }

        const float* hc = &hbuf[cur][q][0];
        float4 h4[8];
#pragma unroll
        for (int i = 0; i < 8; ++i) h4[i] = *(const float4*)(hc + q * 32 + i * 4);
        const float hold = hc[g];

        // 2 independent chains of 16 FMAs per gate
        float a0 = 0.f, a1 = 0.f, a2 = 0.f, c0 = 0.f, c1 = 0.f, c2 = 0.f;
#pragma unroll
        for (int i = 0; i < 4; ++i) {
            a0 = fmaf(w0[i].x, h4[i].x, a0); a0 = fmaf(w0[i].y, h4[i].y, a0);
            a0 = fmaf(w0[i].z, h4[i].z, a0); a0 = fmaf(w0[i].w, h4[i].w, a0);
            a1 = fmaf(w1[i].x, h4[i].x, a1); a1 = fmaf(w1[i].y, h4[i].y, a1);
            a1 = fmaf(w1[i].z, h4[i].z, a1); a1 = fmaf(w1[i].w, h4[i].w, a1);
            a2 = fmaf(w2[i].x, h4[i].x, a2); a2 = fmaf(w2[i].y, h4[i].y, a2);
            a2 = fmaf(w2[i].z, h4[i].z, a2); a2 = fmaf(w2[i].w, h4[i].w, a2);
        }
#pragma unroll
        for (int i = 4; i < 8; ++i) {
            c0 = fmaf(w0[i].x, h4[i].x, c0); c0 = fmaf(w0[i].y, h4[i].y, c0);
            c0 = fmaf(w0[i].z, h4[i].z, c0); c0 = fmaf(w0[i].w, h4[i].w, c0);
            c1 = fmaf(w1[i].x, h4[i].x, c1); c1 = fmaf(w1[i].y, h4[i].y, c1);
            c1 = fmaf(w1[i].z, h4[i].z, c1); c1 = fmaf(w1[i].w, h4[i].w, c1);
            c2 = fmaf(w2[i].x, h4[i].x, c2); c2 = fmaf(w2[i].y, h4[i].y, c2);
            c2 = fmaf(w2[i].z, h4[i].z, c2); c2 = fmaf(w2[i].w, h4[i].w, c2);
        }
        a0 += c0; a1 += c1; a2 += c2;
        a0 += __shfl_xor(a0, 1); a0 += __shfl_xor(a0, 2);
        a1 += __shfl_xor(a1, 1); a1 += __shfl_xor(a1, 2);
        a2 += __shfl_xor(a2, 1); a2 += __shfl_xor(a2, 2);

        float xr = p0r + a0 + bh0;  xr = fminf(fmaxf(xr, -60.f), 60.f);
        float xz = p0z + a1 + bh1;  xz = fminf(fmaxf(xz, -60.f), 60.f);
        float r = frcp(1.f + __expf(-xr));
        float z = frcp(1.f + __expf(-xz));
        float xn = p0n + r * (a2 + bh2); xn = fminf(fmaxf(xn, -15.f), 15.f);
        float e2 = __expf(-2.f * xn);
        float n = (1.f - e2) * frcp(1.f + e2);
        float hnew = (1.f - z) * n + z * hold;

        hbuf[cur ^ 1][q][g] = hnew;            // all 4 copies updated
        if (q == 0) {
            ctxb[((size_t)t * 128 + b) * 128 + g] = f2b(hnew);
            if (t == 255) out_hidden[b * 128 + g] = hnew;
        }
        p0r = p1r; p0z = p1z; p0n = p1n;
        p1r = p2r; p1z = p2z; p1n = p2n;
        __syncthreads();
    }
}

// ---------------- fused CPC: MFMA GEMM1 (P^T) -> MFMA GEMM2 (Sc) -> reg softmax ----------------
__global__ __launch_bounds__(256) void k_cpc(const unsigned short* __restrict__ ctxb,
                                             const unsigned short* __restrict__ encb,
                                             const float* __restrict__ pW,
                                             const float* __restrict__ pb,
                                             float* __restrict__ lp,
                                             float* __restrict__ cp) {
    const int s = blockIdx.x, o = blockIdx.y;
    __shared__ __align__(16) char bufA[32768];   // ctx [c][d] -> later tgt [b][e]
    __shared__ __align__(16) char bufB[32768];   // Wo  [e][d] -> later P   [c][e]
    __shared__ float rowm[2][128], rowsum[2][128];
    __shared__ float Lrow[128], diagv[128];
    __shared__ float colv[2][128];
    __shared__ int   colix[2][128];
    __shared__ float fin[4];

    const int tid = threadIdx.x;
    const int lane = tid & 63, wid = tid >> 6;
    const int wy = wid >> 1, wx = wid & 1;
    const int g = lane >> 4, ln = lane & 15;

    {
        const unsigned short* src = ctxb + (size_t)(TIn + s) * (128 * 128);
        const float* wsrc = pW + (size_t)o * (128 * 128);
#pragma unroll
        for (int it = 0; it < 8; ++it) {
            int G = tid + it * 256;
            int r = G >> 4, go = G & 15;
            *(uint4*)(bufA + (r * 16 + (go ^ (r & 7))) * 16) = *(const uint4*)(src + r * 128 + go * 8);
            float4 f0 = *(const float4*)(wsrc + r * 128 + go * 8);
            float4 f1 = *(const float4*)(wsrc + r * 128 + go * 8 + 4);
            uint4 w; w.x = pk2(f0.x, f0.y); w.y = pk2(f0.z, f0.w);
            w.z = pk2(f1.x, f1.y); w.w = pk2(f1.z, f1.w);
            *(uint4*)(bufB + (r * 16 + (go ^ (r & 7))) * 16) = w;
        }
    }
    __syncthreads();

    // GEMM1: P^T[e][c] = Wo[e][:] . ctx[c][:]
    f32x4 acc[4][4];
#pragma unroll
    for (int i = 0; i < 4; ++i)
#pragma unroll
        for (int j = 0; j < 4; ++j) acc[i][j] = (f32x4){0.f, 0.f, 0.f, 0.f};
#pragma unroll
    for (int ks = 0; ks < 4; ++ks) {
        bf16x8 af[4], bfr[4];
        const int kb = ks * 64 + g * 16;
#pragma unroll
        for (int mi = 0; mi < 4; ++mi) {
            int r = wy * 64 + mi * 16 + ln;
            af[mi] = *(const bf16x8*)(bufB + r * 256 + (kb ^ ((r & 7) << 4)));
        }
#pragma unroll
        for (int ni = 0; ni < 4; ++ni) {
            int r = wx * 64 + ni * 16 + ln;
            bfr[ni] = *(const bf16x8*)(bufA + r * 256 + (kb ^ ((r & 7) << 4)));
        }
#pragma unroll
        for (int mi = 0; mi < 4; ++mi)
#pragma unroll
            for (int ni = 0; ni < 4; ++ni)
                acc[mi][ni] = __builtin_amdgcn_mfma_f32_16x16x32_bf16(af[mi], bfr[ni], acc[mi][ni], 0, 0, 0);
    }
    __syncthreads();

    // write P[c][e] (bias, bf16, swizzled) into bufB; stage tgt into bufA
    {
        float pbv[4][4];
#pragma unroll
        for (int mi = 0; mi < 4; ++mi) {
            int e0 = wy * 64 + mi * 16 + g * 4;
#pragma unroll
            for (int jj = 0; jj < 4; ++jj) pbv[mi][jj] = pb[o * 128 + e0 + jj];
        }
#pragma unroll
        for (int mi = 0; mi < 4; ++mi) {
            int e0 = wy * 64 + mi * 16 + g * 4;
#pragma unroll
            for (int ni = 0; ni < 4; ++ni) {
                int c = wx * 64 + ni * 16 + ln;
                unsigned int lo = pk2(acc[mi][ni][0] + pbv[mi][0], acc[mi][ni][1] + pbv[mi][1]);
                unsigned int hi = pk2(acc[mi][ni][2] + pbv[mi][2], acc[mi][ni][3] + pbv[mi][3]);
                int byteoff = c * 256 + ((e0 * 2) ^ ((c & 7) << 4));
                *(uint2*)(bufB + byteoff) = make_uint2(lo, hi);
            }
        }
        const unsigned short* tsrc = encb + (size_t)(TIn + 1 + o + s) * (128 * 128);
#pragma unroll
        for (int it = 0; it < 8; ++it) {
            int G = tid + it * 256;
            int r = G >> 4, go = G & 15;
            *(uint4*)(bufA + (r * 16 + (go ^ (r & 7))) * 16) = *(const uint4*)(tsrc + r * 128 + go * 8);
        }
    }
    __syncthreads();

    // GEMM2: Sc[b][c] = tgt[b][:] . P[c][:]
#pragma unroll
    for (int i = 0; i < 4; ++i)
#pragma unroll
        for (int j = 0; j < 4; ++j) acc[i][j] = (f32x4){0.f, 0.f, 0.f, 0.f};
#pragma unroll
    for (int ks = 0; ks < 4; ++ks) {
        bf16x8 af[4], bfr[4];
        const int kb = ks * 64 + g * 16;
#pragma unroll
        for (int mi = 0; mi < 4; ++mi) {
            int r = wy * 64 + mi * 16 + ln;
            af[mi] = *(const bf16x8*)(bufA + r * 256 + (kb ^ ((r & 7) << 4)));
        }
#pragma unroll
        for (int ni = 0; ni < 4; ++ni) {
            int r = wx * 64 + ni * 16 + ln;
            bfr[ni] = *(const bf16x8*)(bufB + r * 256 + (kb ^ ((r & 7) << 4)));
        }
#pragma unroll
        for (int mi = 0; mi < 4; ++mi)
#pragma unroll
            for (int ni = 0; ni < 4; ++ni)
                acc[mi][ni] = __builtin_amdgcn_mfma_f32_16x16x32_bf16(af[mi], bfr[ni], acc[mi][ni], 0, 0, 0);
    }

    // row softmax stats + diag, in-register
#pragma unroll
    for (int mi = 0; mi < 4; ++mi) {
#pragma unroll
        for (int jj = 0; jj < 4; ++jj) {
            float m = fmaxf(fmaxf(acc[mi][0][jj], acc[mi][1][jj]),
                            fmaxf(acc[mi][2][jj], acc[mi][3][jj]));
            m = fmaxf(m, __shfl_xor(m, 1)); m = fmaxf(m, __shfl_xor(m, 2));
            m = fmaxf(m, __shfl_xor(m, 4)); m = fmaxf(m, __shfl_xor(m, 8));
            float sm = __expf(acc[mi][0][jj] - m) + __expf(acc[mi][1][jj] - m)
                     + __expf(acc[mi][2][jj] - m) + __expf(acc[mi][3][jj] - m);
            sm += __shfl_xor(sm, 1); sm += __shfl_xor(sm, 2);
            sm += __shfl_xor(sm, 4); sm += __shfl_xor(sm, 8);
            int b = wy * 64 + mi * 16 + g * 4 + jj;
            if (ln == 0) { rowm[wx][b] = m; rowsum[wx][b] = sm; }
            if (wy == wx && ln == g * 4 + jj) diagv[b] = acc[mi][mi][jj];
        }
    }
    __syncthreads();
    if (tid < 128) {
        float m0 = rowm[0][tid], m1 = rowm[1][tid];
        float mm = fmaxf(m0, m1);
        float ss = rowsum[0][tid] * __expf(m0 - mm) + rowsum[1][tid] * __expf(m1 - mm);
        Lrow[tid] = mm + __logf(ss);
    }
    __syncthreads();

    float Lr[4][4];
#pragma unroll
    for (int mi = 0; mi < 4; ++mi)
#pragma unroll
        for (int jj = 0; jj < 4; ++jj) Lr[mi][jj] = Lrow[wy * 64 + mi * 16 + g * 4 + jj];

#pragma unroll
    for (int ni = 0; ni < 4; ++ni) {
        float best = NEG_INF; int bidx = 0x7fffffff;
#pragma unroll
        for (int mi = 0; mi < 4; ++mi)
#pragma unroll
            for (int jj = 0; jj < 4; ++jj) {
                float v = acc[mi][ni][jj] - Lr[mi][jj];
                int r = wy * 64 + mi * 16 + g * 4 + jj;
                if (v > best) { best = v; bidx = r; }
            }
#pragma unroll
        for (int mask = 16; mask <= 32; mask <<= 1) {
            float ov = __shfl_xor(best, mask);
            int   oi = __shfl_xor(bidx, mask);
            if (ov > best || (ov == best && oi < bidx)) { best = ov; bidx = oi; }
        }
        if (g == 0) {
            int c = wx * 64 + ni * 16 + ln;
            colv[wy][c] = best; colix[wy][c] = bidx;
        }
    }
    __syncthreads();

    float lsum = 0.f, csum = 0.f;
    if (tid < 128) {
        lsum = diagv[tid] - Lrow[tid];
        float v0 = colv[0][tid], v1 = colv[1][tid];
        int ix = (v1 > v0) ? colix[1][tid] : colix[0][tid];
        csum = (ix == tid) ? 1.f : 0.f;
    }
#pragma unroll
    for (int off = 32; off > 0; off >>= 1) {
        lsum += __shfl_down(lsum, off);
        csum += __shfl_down(csum, off);
    }
    if (lane == 0 && wid < 2) { fin[wid] = lsum; fin[2 + wid] = csum; }
    __syncthreads();
    if (tid == 0) {
        lp[o * Sn + s] = fin[0] + fin[1];
        cp[o * Sn + s] = fin[2] + fin[3];
    }
}

// ---------------- final reduction ----------------
__global__ __launch_bounds__(256) void k_final(const float* __restrict__ lp,
                                               const float* __restrict__ cp,
                                               float* __restrict__ out) {
    __shared__ float sl[256], sc2[256];
    const int tid = threadIdx.x;
    float l = 0.f, c = 0.f;
    for (int i = tid; i < TOn * Sn; i += 256) { l += lp[i]; c += cp[i]; }
    sl[tid] = l; sc2[tid] = c;
    __syncthreads();
    for (int s = 128; s > 0; s >>= 1) {
        if (tid < s) { sl[tid] += sl[tid + s]; sc2[tid] += sc2[tid + s]; }
        __syncthreads();
    }
    if (tid == 0) {
        out[0] = sc2[0] / DENOMF;      // accuracy
        out[1] = -sl[0] / DENOMF;      // loss
    }
}

extern "C" void kernel_launch(void* const* d_in, const int* in_sizes, int n_in,
                              void* d_out, int out_size, void* d_ws, size_t ws_size,
                              hipStream_t stream) {
    const float* X      = (const float*)d_in[0];
    const float* conv_w = (const float*)d_in[1];
    const float* conv_b = (const float*)d_in[2];
    const float* W_ih   = (const float*)d_in[3];
    const float* W_hh   = (const float*)d_in[4];
    const float* b_ih   = (const float*)d_in[5];
    const float* b_hh   = (const float*)d_in[6];
    const float* pred_W = (const float*)d_in[7];
    const float* pred_b = (const float*)d_in[8];
    float* out = (float*)d_out;
    char*  ws  = (char*)d_ws;

    unsigned short* encb = (unsigned short*)(ws + OFFB_ENC);
    unsigned short* ctxb = (unsigned short*)(ws + OFFB_CTX);
    float*          gi   = (float*)(ws + OFFB_GI);
    unsigned short* BcT  = (unsigned short*)(ws + OFFB_BCT);
    unsigned short* Wt   = (unsigned short*)(ws + OFFB_WT);
    float*          lp   = (float*)(ws + OFFB_LP);
    float*          cp   = (float*)(ws + OFFB_CP);

    k_prep <<<dim3(384),     dim3(256), 0, stream>>>(conv_w, BcT, W_ih, Wt);
    k_conv <<<dim3(256),     dim3(256), 0, stream>>>(X, BcT, conv_b, encb);
    k_gi   <<<dim3(256, 3),  dim3(256), 0, stream>>>(encb, Wt, b_ih, gi);
    k_gru  <<<dim3(128),     dim3(512), 0, stream>>>(gi, W_hh, b_hh, ctxb, out + 2);
    k_cpc  <<<dim3(Sn, TOn), dim3(256), 0, stream>>>(ctxb, encb, pred_W, pred_b, lp, cp);
    k_final<<<dim3(1),       dim3(256), 0, stream>>>(lp, cp, out);
}

// Round 4
// 272.340 us; speedup vs baseline: 2.2500x; 1.0073x over previous
//
#include <hip/hip_runtime.h>
#include <math.h>

typedef __attribute__((ext_vector_type(8))) short bf16x8;
typedef __attribute__((ext_vector_type(4))) float f32x4;

#define Bdim 128
#define Cdim 12
#define Ddim 128
#define Tdim 256
#define TOn  8
#define TIn  64
#define Sn   183
#define DENOMF 187392.0f
#define NEG_INF -3.402823466e38f

// ---------------- workspace layout (bytes) ----------------
#define OFFB_ENC 0
#define OFFB_CTX 8388608
#define OFFB_GI  16777216
#define OFFB_BCT 67108864
#define OFFB_WT  67305472
#define OFFB_LP  67403776
#define OFFB_CP  67409632

__device__ __forceinline__ float frcp(float x) { return __builtin_amdgcn_rcpf(x); }

__device__ __forceinline__ unsigned short f2b(float x) {
    unsigned int u = __builtin_bit_cast(unsigned int, x);
    u += 0x7FFFu + ((u >> 16) & 1u);
    return (unsigned short)(u >> 16);
}
__device__ __forceinline__ unsigned int pk2(float a, float b) {
    return (unsigned int)f2b(a) | ((unsigned int)f2b(b) << 16);
}

// opaque 16B load: compiler cannot rematerialize it inside loops,
// so the result MUST stay register-resident.
__device__ __forceinline__ float4 ldg4_pin(const float* p) {
    float4 r;
    asm volatile("global_load_dwordx4 %0, %1, off\n\ts_waitcnt vmcnt(0)"
                 : "=v"(r) : "v"(p) : "memory");
    return r;
}

// ---------------- prep: weight transposes -> bf16 ----------------
__global__ __launch_bounds__(256) void k_prep(const float* __restrict__ conv_w,
                                              unsigned short* __restrict__ BcT,
                                              const float* __restrict__ W_ih,
                                              unsigned short* __restrict__ Wt) {
    int id = blockIdx.x * 256 + threadIdx.x;
    if (id < 128 * 768) {
        int d = id / 768, klin = id % 768;
        int kt = klin / 12, c = klin % 12;
        BcT[id] = f2b(conv_w[d * 768 + c * 64 + kt]);   // BcT[d][kt*12+c]
    }
    if (id < 384 * 128) Wt[id] = f2b(W_ih[id]);          // Wt[n][k]
}

// ---------------- conv as bf16 MFMA GEMM ----------------
__global__ __launch_bounds__(256) void k_conv(const float* __restrict__ X,
                                              const unsigned short* __restrict__ BcT,
                                              const float* __restrict__ conv_b,
                                              unsigned short* __restrict__ encb) {
    const int t = blockIdx.x;
    __shared__ __align__(16) char As[16384];   // [b=128][k=64] bf16, swizzled
    __shared__ __align__(16) char Bs[16384];   // [d=128][k=64] bf16, swizzled
    const int tid = threadIdx.x;
    const int lane = tid & 63, wid = tid >> 6;
    const int wy = wid >> 1, wx = wid & 1;
    const int g = lane >> 4, ln = lane & 15;

    f32x4 acc[4][4];
#pragma unroll
    for (int i = 0; i < 4; ++i)
#pragma unroll
        for (int j = 0; j < 4; ++j) acc[i][j] = (f32x4){0.f, 0.f, 0.f, 0.f};

    for (int kc = 0; kc < 768; kc += 64) {
        __syncthreads();
#pragma unroll
        for (int it = 0; it < 4; ++it) {
            int G = tid + it * 256;             // granule 0..1023 (16B each)
            int r = G >> 3, go = G & 7;
            const float* src = X + (size_t)r * (16384 * 12) + t * 768 + kc + go * 8;
            float4 f0 = *(const float4*)src;
            float4 f1 = *(const float4*)(src + 4);
            uint4 w; w.x = pk2(f0.x, f0.y); w.y = pk2(f0.z, f0.w);
            w.z = pk2(f1.x, f1.y); w.w = pk2(f1.z, f1.w);
            *(uint4*)(As + (r * 8 + (go ^ (r & 7))) * 16) = w;
            uint4 v = *(const uint4*)(BcT + (size_t)r * 768 + kc + go * 8);
            *(uint4*)(Bs + (r * 8 + (go ^ (r & 7))) * 16) = v;
        }
        __syncthreads();
#pragma unroll
        for (int ks = 0; ks < 2; ++ks) {
            bf16x8 af[4], bfr[4];
            const int kb = ks * 64 + g * 16;
#pragma unroll
            for (int mi = 0; mi < 4; ++mi) {
                int r = wy * 64 + mi * 16 + ln;
                af[mi] = *(const bf16x8*)(As + r * 128 + (kb ^ ((r & 7) << 4)));
            }
#pragma unroll
            for (int ni = 0; ni < 4; ++ni) {
                int r = wx * 64 + ni * 16 + ln;
                bfr[ni] = *(const bf16x8*)(Bs + r * 128 + (kb ^ ((r & 7) << 4)));
            }
#pragma unroll
            for (int mi = 0; mi < 4; ++mi)
#pragma unroll
                for (int ni = 0; ni < 4; ++ni)
                    acc[mi][ni] = __builtin_amdgcn_mfma_f32_16x16x32_bf16(af[mi], bfr[ni], acc[mi][ni], 0, 0, 0);
        }
    }
    float cb[4];
#pragma unroll
    for (int ni = 0; ni < 4; ++ni) cb[ni] = conv_b[wx * 64 + ni * 16 + ln];
    unsigned short* dst = encb + (size_t)t * (128 * 128);
#pragma unroll
    for (int mi = 0; mi < 4; ++mi)
#pragma unroll
        for (int jj = 0; jj < 4; ++jj) {
            int b = wy * 64 + mi * 16 + g * 4 + jj;
#pragma unroll
            for (int ni = 0; ni < 4; ++ni) {
                int d = wx * 64 + ni * 16 + ln;
                dst[b * 128 + d] = f2b(fmaxf(acc[mi][ni][jj] + cb[ni], 0.f));
            }
        }
}

// ---------------- gi = enc @ W_ih^T + b_ih  (bf16 MFMA, fp32 out) ----------------
__global__ __launch_bounds__(256) void k_gi(const unsigned short* __restrict__ encb,
                                            const unsigned short* __restrict__ Wt,
                                            const float* __restrict__ b_ih,
                                            float* __restrict__ gi) {
    const int mt = blockIdx.x, nt = blockIdx.y;
    __shared__ __align__(16) char As[32768];   // [m=128][k=128]
    __shared__ __align__(16) char Bs[32768];   // [n=128][k=128]
    const int tid = threadIdx.x;
    const int lane = tid & 63, wid = tid >> 6;
    const int wy = wid >> 1, wx = wid & 1;
    const int g = lane >> 4, ln = lane & 15;

    {
        const unsigned short* asrc = encb + (size_t)mt * (128 * 128);
        const unsigned short* bsrc = Wt + (size_t)nt * (128 * 128);
#pragma unroll
        for (int it = 0; it < 8; ++it) {
            int G = tid + it * 256;             // granule 0..2047
            int r = G >> 4, go = G & 15;
            *(uint4*)(As + (r * 16 + (go ^ (r & 7))) * 16) = *(const uint4*)(asrc + r * 128 + go * 8);
            *(uint4*)(Bs + (r * 16 + (go ^ (r & 7))) * 16) = *(const uint4*)(bsrc + r * 128 + go * 8);
        }
    }
    __syncthreads();

    f32x4 acc[4][4];
#pragma unroll
    for (int i = 0; i < 4; ++i)
#pragma unroll
        for (int j = 0; j < 4; ++j) acc[i][j] = (f32x4){0.f, 0.f, 0.f, 0.f};
#pragma unroll
    for (int ks = 0; ks < 4; ++ks) {
        bf16x8 af[4], bfr[4];
        const int kb = ks * 64 + g * 16;
#pragma unroll
        for (int mi = 0; mi < 4; ++mi) {
            int r = wy * 64 + mi * 16 + ln;
            af[mi] = *(const bf16x8*)(As + r * 256 + (kb ^ ((r & 7) << 4)));
        }
#pragma unroll
        for (int ni = 0; ni < 4; ++ni) {
            int r = wx * 64 + ni * 16 + ln;
            bfr[ni] = *(const bf16x8*)(Bs + r * 256 + (kb ^ ((r & 7) << 4)));
        }
#pragma unroll
        for (int mi = 0; mi < 4; ++mi)
#pragma unroll
            for (int ni = 0; ni < 4; ++ni)
                acc[mi][ni] = __builtin_amdgcn_mfma_f32_16x16x32_bf16(af[mi], bfr[ni], acc[mi][ni], 0, 0, 0);
    }
    float bv[4];
#pragma unroll
    for (int ni = 0; ni < 4; ++ni) bv[ni] = b_ih[nt * 128 + wx * 64 + ni * 16 + ln];
#pragma unroll
    for (int mi = 0; mi < 4; ++mi)
#pragma unroll
        for (int jj = 0; jj < 4; ++jj) {
            int m = mt * 128 + wy * 64 + mi * 16 + g * 4 + jj;
#pragma unroll
            for (int ni = 0; ni < 4; ++ni) {
                int n = nt * 128 + wx * 64 + ni * 16 + ln;
                gi[(size_t)m * 384 + n] = acc[mi][ni][jj] + bv[ni];
            }
        }
}

// ---------------- GRU v3: weights pinned in VGPRs via opaque asm loads ----------------
// thread (g = tid>>2, q = tid&3): W_hh rows {g, g+128, g+256}, k-quarter q*32..+32
__global__ __launch_bounds__(512, 2) void k_gru(const float* __restrict__ gi,
                                                const float* __restrict__ Whh,
                                                const float* __restrict__ bhh,
                                                unsigned short* __restrict__ ctxb,
                                                float* __restrict__ out_hidden) {
    const int b = blockIdx.x;
    const int tid = threadIdx.x;
    const int g = tid >> 2, q = tid & 3;
    // copy q lives at word base (buf*4+q)*136; 136%32==8 -> copy q banks offset 8q
    __shared__ float hbuf[2][4][136];

    float4 w0[8], w1[8], w2[8];
    {
        const float* W0 = Whh + (size_t)g * 128 + q * 32;
        const float* W1 = Whh + (size_t)(g + 128) * 128 + q * 32;
        const float* W2 = Whh + (size_t)(g + 256) * 128 + q * 32;
#pragma unroll
        for (int i = 0; i < 8; ++i) {
            w0[i] = ldg4_pin(W0 + i * 4);
            w1[i] = ldg4_pin(W1 + i * 4);
            w2[i] = ldg4_pin(W2 + i * 4);
        }
    }
    const float bh0 = bhh[g], bh1 = bhh[g + 128], bh2 = bhh[g + 256];

    hbuf[0][q][g] = 0.f;

    // depth-2 prefetch of gate pre-activations
    float p0r = gi[(size_t)b * 384 + g];
    float p0z = gi[(size_t)b * 384 + 128 + g];
    float p0n = gi[(size_t)b * 384 + 256 + g];
    float p1r = gi[((size_t)128 + b) * 384 + g];
    float p1z = gi[((size_t)128 + b) * 384 + 128 + g];
    float p1n = gi[((size_t)128 + b) * 384 + 256 + g];
    __syncthreads();

    for (int t = 0; t < 256; ++t) {
        const int cur = t & 1;
        // issue prefetch for t+2 first (longest latency)
        float p2r = 0.f, p2z = 0.f, p2n = 0.f;
        if (t + 2 < 256) {
            const float* gp = gi + ((size_t)(t + 2) * 128 + b) * 384;
            p2r = gp[g]; p2z = gp[128 + g]; p2n = gp[256 + g];
        }

        const float* hc = &hbuf[cur][q][0];
        float4 h4[8];
#pragma unroll
        for (int i = 0; i < 8; ++i) h4[i] = *(const float4*)(hc + q * 32 + i * 4);
        const float hold = hc[g];

        // 2 independent chains of 16 FMAs per gate
        float a0 = 0.f, a1 = 0.f, a2 = 0.f, c0 = 0.f, c1 = 0.f, c2 = 0.f;
#pragma unroll
        for (int i = 0; i < 4; ++i) {
            a0 = fmaf(w0[i].x, h4[i].x, a0); a0 = fmaf(w0[i].y, h4[i].y, a0);
            a0 = fmaf(w0[i].z, h4[i].z, a0); a0 = fmaf(w0[i].w, h4[i].w, a0);
            a1 = fmaf(w1[i].x, h4[i].x, a1); a1 = fmaf(w1[i].y, h4[i].y, a1);
            a1 = fmaf(w1[i].z, h4[i].z, a1); a1 = fmaf(w1[i].w, h4[i].w, a1);
            a2 = fmaf(w2[i].x, h4[i].x, a2); a2 = fmaf(w2[i].y, h4[i].y, a2);
            a2 = fmaf(w2[i].z, h4[i].z, a2); a2 = fmaf(w2[i].w, h4[i].w, a2);
        }
#pragma unroll
        for (int i = 4; i < 8; ++i) {
            c0 = fmaf(w0[i].x, h4[i].x, c0); c0 = fmaf(w0[i].y, h4[i].y, c0);
            c0 = fmaf(w0[i].z, h4[i].z, c0); c0 = fmaf(w0[i].w, h4[i].w, c0);
            c1 = fmaf(w1[i].x, h4[i].x, c1); c1 = fmaf(w1[i].y, h4[i].y, c1);
            c1 = fmaf(w1[i].z, h4[i].z, c1); c1 = fmaf(w1[i].w, h4[i].w, c1);
            c2 = fmaf(w2[i].x, h4[i].x, c2); c2 = fmaf(w2[i].y, h4[i].y, c2);
            c2 = fmaf(w2[i].z, h4[i].z, c2); c2 = fmaf(w2[i].w, h4[i].w, c2);
        }
        a0 += c0; a1 += c1; a2 += c2;
        a0 += __shfl_xor(a0, 1); a0 += __shfl_xor(a0, 2);
        a1 += __shfl_xor(a1, 1); a1 += __shfl_xor(a1, 2);
        a2 += __shfl_xor(a2, 1); a2 += __shfl_xor(a2, 2);

        float xr = p0r + a0 + bh0;  xr = fminf(fmaxf(xr, -60.f), 60.f);
        float xz = p0z + a1 + bh1;  xz = fminf(fmaxf(xz, -60.f), 60.f);
        float r = frcp(1.f + __expf(-xr));
        float z = frcp(1.f + __expf(-xz));
        float xn = p0n + r * (a2 + bh2); xn = fminf(fmaxf(xn, -15.f), 15.f);
        float e2 = __expf(-2.f * xn);
        float n = (1.f - e2) * frcp(1.f + e2);
        float hnew = (1.f - z) * n + z * hold;

        hbuf[cur ^ 1][q][g] = hnew;            // all 4 copies updated
        if (q == 0) {
            ctxb[((size_t)t * 128 + b) * 128 + g] = f2b(hnew);
            if (t == 255) out_hidden[b * 128 + g] = hnew;
        }
        p0r = p1r; p0z = p1z; p0n = p1n;
        p1r = p2r; p1z = p2z; p1n = p2n;
        __syncthreads();
    }
}

// ---------------- fused CPC: MFMA GEMM1 (P^T) -> MFMA GEMM2 (Sc) -> reg softmax ----------------
__global__ __launch_bounds__(256) void k_cpc(const unsigned short* __restrict__ ctxb,
                                             const unsigned short* __restrict__ encb,
                                             const float* __restrict__ pW,
                                             const float* __restrict__ pb,
                                             float* __restrict__ lp,
                                             float* __restrict__ cp) {
    const int s = blockIdx.x, o = blockIdx.y;
    __shared__ __align__(16) char bufA[32768];   // ctx [c][d] -> later tgt [b][e]
    __shared__ __align__(16) char bufB[32768];   // Wo  [e][d] -> later P   [c][e]
    __shared__ float rowm[2][128], rowsum[2][128];
    __shared__ float Lrow[128], diagv[128];
    __shared__ float colv[2][128];
    __shared__ int   colix[2][128];
    __shared__ float fin[4];

    const int tid = threadIdx.x;
    const int lane = tid & 63, wid = tid >> 6;
    const int wy = wid >> 1, wx = wid & 1;
    const int g = lane >> 4, ln = lane & 15;

    {
        const unsigned short* src = ctxb + (size_t)(TIn + s) * (128 * 128);
        const float* wsrc = pW + (size_t)o * (128 * 128);
#pragma unroll
        for (int it = 0; it < 8; ++it) {
            int G = tid + it * 256;
            int r = G >> 4, go = G & 15;
            *(uint4*)(bufA + (r * 16 + (go ^ (r & 7))) * 16) = *(const uint4*)(src + r * 128 + go * 8);
            float4 f0 = *(const float4*)(wsrc + r * 128 + go * 8);
            float4 f1 = *(const float4*)(wsrc + r * 128 + go * 8 + 4);
            uint4 w; w.x = pk2(f0.x, f0.y); w.y = pk2(f0.z, f0.w);
            w.z = pk2(f1.x, f1.y); w.w = pk2(f1.z, f1.w);
            *(uint4*)(bufB + (r * 16 + (go ^ (r & 7))) * 16) = w;
        }
    }
    __syncthreads();

    // GEMM1: P^T[e][c] = Wo[e][:] . ctx[c][:]
    f32x4 acc[4][4];
#pragma unroll
    for (int i = 0; i < 4; ++i)
#pragma unroll
        for (int j = 0; j < 4; ++j) acc[i][j] = (f32x4){0.f, 0.f, 0.f, 0.f};
#pragma unroll
    for (int ks = 0; ks < 4; ++ks) {
        bf16x8 af[4], bfr[4];
        const int kb = ks * 64 + g * 16;
#pragma unroll
        for (int mi = 0; mi < 4; ++mi) {
            int r = wy * 64 + mi * 16 + ln;
            af[mi] = *(const bf16x8*)(bufB + r * 256 + (kb ^ ((r & 7) << 4)));
        }
#pragma unroll
        for (int ni = 0; ni < 4; ++ni) {
            int r = wx * 64 + ni * 16 + ln;
            bfr[ni] = *(const bf16x8*)(bufA + r * 256 + (kb ^ ((r & 7) << 4)));
        }
#pragma unroll
        for (int mi = 0; mi < 4; ++mi)
#pragma unroll
            for (int ni = 0; ni < 4; ++ni)
                acc[mi][ni] = __builtin_amdgcn_mfma_f32_16x16x32_bf16(af[mi], bfr[ni], acc[mi][ni], 0, 0, 0);
    }
    __syncthreads();

    // write P[c][e] (bias, bf16, swizzled) into bufB; stage tgt into bufA
    {
        float pbv[4][4];
#pragma unroll
        for (int mi = 0; mi < 4; ++mi) {
            int e0 = wy * 64 + mi * 16 + g * 4;
#pragma unroll
            for (int jj = 0; jj < 4; ++jj) pbv[mi][jj] = pb[o * 128 + e0 + jj];
        }
#pragma unroll
        for (int mi = 0; mi < 4; ++mi) {
            int e0 = wy * 64 + mi * 16 + g * 4;
#pragma unroll
            for (int ni = 0; ni < 4; ++ni) {
                int c = wx * 64 + ni * 16 + ln;
                unsigned int lo = pk2(acc[mi][ni][0] + pbv[mi][0], acc[mi][ni][1] + pbv[mi][1]);
                unsigned int hi = pk2(acc[mi][ni][2] + pbv[mi][2], acc[mi][ni][3] + pbv[mi][3]);
                int byteoff = c * 256 + ((e0 * 2) ^ ((c & 7) << 4));
                *(uint2*)(bufB + byteoff) = make_uint2(lo, hi);
            }
        }
        const unsigned short* tsrc = encb + (size_t)(TIn + 1 + o + s) * (128 * 128);
#pragma unroll
        for (int it = 0; it < 8; ++it) {
            int G = tid + it * 256;
            int r = G >> 4, go = G & 15;
            *(uint4*)(bufA + (r * 16 + (go ^ (r & 7))) * 16) = *(const uint4*)(tsrc + r * 128 + go * 8);
        }
    }
    __syncthreads();

    // GEMM2: Sc[b][c] = tgt[b][:] . P[c][:]
#pragma unroll
    for (int i = 0; i < 4; ++i)
#pragma unroll
        for (int j = 0; j < 4; ++j) acc[i][j] = (f32x4){0.f, 0.f, 0.f, 0.f};
#pragma unroll
    for (int ks = 0; ks < 4; ++ks) {
        bf16x8 af[4], bfr[4];
        const int kb = ks * 64 + g * 16;
#pragma unroll
        for (int mi = 0; mi < 4; ++mi) {
            int r = wy * 64 + mi * 16 + ln;
            af[mi] = *(const bf16x8*)(bufA + r * 256 + (kb ^ ((r & 7) << 4)));
        }
#pragma unroll
        for (int ni = 0; ni < 4; ++ni) {
            int r = wx * 64 + ni * 16 + ln;
            bfr[ni] = *(const bf16x8*)(bufB + r * 256 + (kb ^ ((r & 7) << 4)));
        }
#pragma unroll
        for (int mi = 0; mi < 4; ++mi)
#pragma unroll
            for (int ni = 0; ni < 4; ++ni)
                acc[mi][ni] = __builtin_amdgcn_mfma_f32_16x16x32_bf16(af[mi], bfr[ni], acc[mi][ni], 0, 0, 0);
    }

    // row softmax stats + diag, in-register
#pragma unroll
    for (int mi = 0; mi < 4; ++mi) {
#pragma unroll
        for (int jj = 0; jj < 4; ++jj) {
            float m = fmaxf(fmaxf(acc[mi][0][jj], acc[mi][1][jj]),
                            fmaxf(acc[mi][2][jj], acc[mi][3][jj]));
            m = fmaxf(m, __shfl_xor(m, 1)); m = fmaxf(m, __shfl_xor(m, 2));
            m = fmaxf(m, __shfl_xor(m, 4)); m = fmaxf(m, __shfl_xor(m, 8));
            float sm = __expf(acc[mi][0][jj] - m) + __expf(acc[mi][1][jj] - m)
                     + __expf(acc[mi][2][jj] - m) + __expf(acc[mi][3][jj] - m);
            sm += __shfl_xor(sm, 1); sm += __shfl_xor(sm, 2);
            sm += __shfl_xor(sm, 4); sm += __shfl_xor(sm, 8);
            int b = wy * 64 + mi * 16 + g * 4 + jj;
            if (ln == 0) { rowm[wx][b] = m; rowsum[wx][b] = sm; }
            if (wy == wx && ln == g * 4 + jj) diagv[b] = acc[mi][mi][jj];
        }
    }
    __syncthreads();
    if (tid < 128) {
        float m0 = rowm[0][tid], m1 = rowm[1][tid];
        float mm = fmaxf(m0, m1);
        float ss = rowsum[0][tid] * __expf(m0 - mm) + rowsum[1][tid] * __expf(m1 - mm);
        Lrow[tid] = mm + __logf(ss);
    }
    __syncthreads();

    float Lr[4][4];
#pragma unroll
    for (int mi = 0; mi < 4; ++mi)
#pragma unroll
        for (int jj = 0; jj < 4; ++jj) Lr[mi][jj] = Lrow[wy * 64 + mi * 16 + g * 4 + jj];

#pragma unroll
    for (int ni = 0; ni < 4; ++ni) {
        float best = NEG_INF; int bidx = 0x7fffffff;
#pragma unroll
        for (int mi = 0; mi < 4; ++mi)
#pragma unroll
            for (int jj = 0; jj < 4; ++jj) {
                float v = acc[mi][ni][jj] - Lr[mi][jj];
                int r = wy * 64 + mi * 16 + g * 4 + jj;
                if (v > best) { best = v; bidx = r; }
            }
#pragma unroll
        for (int mask = 16; mask <= 32; mask <<= 1) {
            float ov = __shfl_xor(best, mask);
            int   oi = __shfl_xor(bidx, mask);
            if (ov > best || (ov == best && oi < bidx)) { best = ov; bidx = oi; }
        }
        if (g == 0) {
            int c = wx * 64 + ni * 16 + ln;
            colv[wy][c] = best; colix[wy][c] = bidx;
        }
    }
    __syncthreads();

    float lsum = 0.f, csum = 0.f;
    if (tid < 128) {
        lsum = diagv[tid] - Lrow[tid];
        float v0 = colv[0][tid], v1 = colv[1][tid];
        int ix = (v1 > v0) ? colix[1][tid] : colix[0][tid];
        csum = (ix == tid) ? 1.f : 0.f;
    }
#pragma unroll
    for (int off = 32; off > 0; off >>= 1) {
        lsum += __shfl_down(lsum, off);
        csum += __shfl_down(csum, off);
    }
    if (lane == 0 && wid < 2) { fin[wid] = lsum; fin[2 + wid] = csum; }
    __syncthreads();
    if (tid == 0) {
        lp[o * Sn + s] = fin[0] + fin[1];
        cp[o * Sn + s] = fin[2] + fin[3];
    }
}

// ---------------- final reduction ----------------
__global__ __launch_bounds__(256) void k_final(const float* __restrict__ lp,
                                               const float* __restrict__ cp,
                                               float* __restrict__ out) {
    __shared__ float sl[256], sc2[256];
    const int tid = threadIdx.x;
    float l = 0.f, c = 0.f;
    for (int i = tid; i < TOn * Sn; i += 256) { l += lp[i]; c += cp[i]; }
    sl[tid] = l; sc2[tid] = c;
    __syncthreads();
    for (int s = 128; s > 0; s >>= 1) {
        if (tid < s) { sl[tid] += sl[tid + s]; sc2[tid] += sc2[tid + s]; }
        __syncthreads();
    }
    if (tid == 0) {
        out[0] = sc2[0] / DENOMF;      // accuracy
        out[1] = -sl[0] / DENOMF;      // loss
    }
}

extern "C" void kernel_launch(void* const* d_in, const int* in_sizes, int n_in,
                              void* d_out, int out_size, void* d_ws, size_t ws_size,
                              hipStream_t stream) {
    const float* X      = (const float*)d_in[0];
    const float* conv_w = (const float*)d_in[1];
    const float* conv_b = (const float*)d_in[2];
    const float* W_ih   = (const float*)d_in[3];
    const float* W_hh   = (const float*)d_in[4];
    const float* b_ih   = (const float*)d_in[5];
    const float* b_hh   = (const float*)d_in[6];
    const float* pred_W = (const float*)d_in[7];
    const float* pred_b = (const float*)d_in[8];
    float* out = (float*)d_out;
    char*  ws  = (char*)d_ws;

    unsigned short* encb = (unsigned short*)(ws + OFFB_ENC);
    unsigned short* ctxb = (unsigned short*)(ws + OFFB_CTX);
    float*          gi   = (float*)(ws + OFFB_GI);
    unsigned short* BcT  = (unsigned short*)(ws + OFFB_BCT);
    unsigned short* Wt   = (unsigned short*)(ws + OFFB_WT);
    float*          lp   = (float*)(ws + OFFB_LP);
    float*          cp   = (float*)(ws + OFFB_CP);

    k_prep <<<dim3(384),     dim3(256), 0, stream>>>(conv_w, BcT, W_ih, Wt);
    k_conv <<<dim3(256),     dim3(256), 0, stream>>>(X, BcT, conv_b, encb);
    k_gi   <<<dim3(256, 3),  dim3(256), 0, stream>>>(encb, Wt, b_ih, gi);
    k_gru  <<<dim3(128),     dim3(512), 0, stream>>>(gi, W_hh, b_hh, ctxb, out + 2);
    k_cpc  <<<dim3(Sn, TOn), dim3(256), 0, stream>>>(ctxb, encb, pred_W, pred_b, lp, cp);
    k_final<<<dim3(1),       dim3(256), 0, stream>>>(lp, cp, out);
}

// Round 5
// 271.754 us; speedup vs baseline: 2.2549x; 1.0022x over previous
//
#include <hip/hip_runtime.h>
#include <math.h>

typedef __attribute__((ext_vector_type(8))) short bf16x8;
typedef __attribute__((ext_vector_type(4))) float f32x4;

#define Bdim 128
#define Cdim 12
#define Ddim 128
#define Tdim 256
#define TOn  8
#define TIn  64
#define Sn   183
#define DENOMF 187392.0f
#define NEG_INF -3.402823466e38f

// ---------------- workspace layout (bytes) ----------------
#define OFFB_ENC 0
#define OFFB_CTX 8388608
#define OFFB_GI  16777216
#define OFFB_BCT 67108864
#define OFFB_WT  67305472
#define OFFB_LP  67403776
#define OFFB_CP  67409632
#define OFFB_WHP 67415488   // W_hh packed bf16 pairs: 384 rows x 64 u32 = 98304 B

__device__ __forceinline__ float frcp(float x) { return __builtin_amdgcn_rcpf(x); }

__device__ __forceinline__ unsigned short f2b(float x) {
    unsigned int u = __builtin_bit_cast(unsigned int, x);
    u += 0x7FFFu + ((u >> 16) & 1u);
    return (unsigned short)(u >> 16);
}
__device__ __forceinline__ unsigned int pk2(float a, float b) {
    return (unsigned int)f2b(a) | ((unsigned int)f2b(b) << 16);
}
__device__ __forceinline__ float b2f_lo(unsigned int w) {
    return __builtin_bit_cast(float, w << 16);
}
__device__ __forceinline__ float b2f_hi(unsigned int w) {
    return __builtin_bit_cast(float, w & 0xffff0000u);
}

// opaque 16B load: compiler cannot rematerialize it inside loops.
__device__ __forceinline__ uint4 ldg4u_pin(const unsigned int* p) {
    uint4 r;
    asm volatile("global_load_dwordx4 %0, %1, off\n\ts_waitcnt vmcnt(0)"
                 : "=v"(r) : "v"(p) : "memory");
    return r;
}

// D = dot2(bf16x2 a, bf16x2 b) + acc   (f32 accumulate)
__device__ __forceinline__ void dot2b(float& acc, unsigned int a, unsigned int b) {
    asm("v_dot2_f32_bf16 %0, %1, %2, %0" : "+v"(acc) : "v"(a), "v"(b));
}

// ---------------- prep: weight transposes -> bf16 ----------------
__global__ __launch_bounds__(256) void k_prep(const float* __restrict__ conv_w,
                                              unsigned short* __restrict__ BcT,
                                              const float* __restrict__ W_ih,
                                              unsigned short* __restrict__ Wt,
                                              const float* __restrict__ W_hh,
                                              unsigned int* __restrict__ Whp) {
    int id = blockIdx.x * 256 + threadIdx.x;
    if (id < 128 * 768) {
        int d = id / 768, klin = id % 768;
        int kt = klin / 12, c = klin % 12;
        BcT[id] = f2b(conv_w[d * 768 + c * 64 + kt]);   // BcT[d][kt*12+c]
    }
    if (id < 384 * 128) Wt[id] = f2b(W_ih[id]);          // Wt[n][k]
    if (id < 384 * 64) {
        int row = id >> 6, k2 = id & 63;
        Whp[id] = pk2(W_hh[row * 128 + 2 * k2], W_hh[row * 128 + 2 * k2 + 1]);
    }
}

// ---------------- conv as bf16 MFMA GEMM ----------------
__global__ __launch_bounds__(256) void k_conv(const float* __restrict__ X,
                                              const unsigned short* __restrict__ BcT,
                                              const float* __restrict__ conv_b,
                                              unsigned short* __restrict__ encb) {
    const int t = blockIdx.x;
    __shared__ __align__(16) char As[16384];   // [b=128][k=64] bf16, swizzled
    __shared__ __align__(16) char Bs[16384];   // [d=128][k=64] bf16, swizzled
    const int tid = threadIdx.x;
    const int lane = tid & 63, wid = tid >> 6;
    const int wy = wid >> 1, wx = wid & 1;
    const int g = lane >> 4, ln = lane & 15;

    f32x4 acc[4][4];
#pragma unroll
    for (int i = 0; i < 4; ++i)
#pragma unroll
        for (int j = 0; j < 4; ++j) acc[i][j] = (f32x4){0.f, 0.f, 0.f, 0.f};

    for (int kc = 0; kc < 768; kc += 64) {
        __syncthreads();
#pragma unroll
        for (int it = 0; it < 4; ++it) {
            int G = tid + it * 256;             // granule 0..1023 (16B each)
            int r = G >> 3, go = G & 7;
            const float* src = X + (size_t)r * (16384 * 12) + t * 768 + kc + go * 8;
            float4 f0 = *(const float4*)src;
            float4 f1 = *(const float4*)(src + 4);
            uint4 w; w.x = pk2(f0.x, f0.y); w.y = pk2(f0.z, f0.w);
            w.z = pk2(f1.x, f1.y); w.w = pk2(f1.z, f1.w);
            *(uint4*)(As + (r * 8 + (go ^ (r & 7))) * 16) = w;
            uint4 v = *(const uint4*)(BcT + (size_t)r * 768 + kc + go * 8);
            *(uint4*)(Bs + (r * 8 + (go ^ (r & 7))) * 16) = v;
        }
        __syncthreads();
#pragma unroll
        for (int ks = 0; ks < 2; ++ks) {
            bf16x8 af[4], bfr[4];
            const int kb = ks * 64 + g * 16;
#pragma unroll
            for (int mi = 0; mi < 4; ++mi) {
                int r = wy * 64 + mi * 16 + ln;
                af[mi] = *(const bf16x8*)(As + r * 128 + (kb ^ ((r & 7) << 4)));
            }
#pragma unroll
            for (int ni = 0; ni < 4; ++ni) {
                int r = wx * 64 + ni * 16 + ln;
                bfr[ni] = *(const bf16x8*)(Bs + r * 128 + (kb ^ ((r & 7) << 4)));
            }
#pragma unroll
            for (int mi = 0; mi < 4; ++mi)
#pragma unroll
                for (int ni = 0; ni < 4; ++ni)
                    acc[mi][ni] = __builtin_amdgcn_mfma_f32_16x16x32_bf16(af[mi], bfr[ni], acc[mi][ni], 0, 0, 0);
        }
    }
    float cb[4];
#pragma unroll
    for (int ni = 0; ni < 4; ++ni) cb[ni] = conv_b[wx * 64 + ni * 16 + ln];
    unsigned short* dst = encb + (size_t)t * (128 * 128);
#pragma unroll
    for (int mi = 0; mi < 4; ++mi)
#pragma unroll
        for (int jj = 0; jj < 4; ++jj) {
            int b = wy * 64 + mi * 16 + g * 4 + jj;
#pragma unroll
            for (int ni = 0; ni < 4; ++ni) {
                int d = wx * 64 + ni * 16 + ln;
                dst[b * 128 + d] = f2b(fmaxf(acc[mi][ni][jj] + cb[ni], 0.f));
            }
        }
}

// ---------------- gi = enc @ W_ih^T + b_ih  (bf16 MFMA, fp32 out) ----------------
__global__ __launch_bounds__(256) void k_gi(const unsigned short* __restrict__ encb,
                                            const unsigned short* __restrict__ Wt,
                                            const float* __restrict__ b_ih,
                                            float* __restrict__ gi) {
    const int mt = blockIdx.x, nt = blockIdx.y;
    __shared__ __align__(16) char As[32768];   // [m=128][k=128]
    __shared__ __align__(16) char Bs[32768];   // [n=128][k=128]
    const int tid = threadIdx.x;
    const int lane = tid & 63, wid = tid >> 6;
    const int wy = wid >> 1, wx = wid & 1;
    const int g = lane >> 4, ln = lane & 15;

    {
        const unsigned short* asrc = encb + (size_t)mt * (128 * 128);
        const unsigned short* bsrc = Wt + (size_t)nt * (128 * 128);
#pragma unroll
        for (int it = 0; it < 8; ++it) {
            int G = tid + it * 256;             // granule 0..2047
            int r = G >> 4, go = G & 15;
            *(uint4*)(As + (r * 16 + (go ^ (r & 7))) * 16) = *(const uint4*)(asrc + r * 128 + go * 8);
            *(uint4*)(Bs + (r * 16 + (go ^ (r & 7))) * 16) = *(const uint4*)(bsrc + r * 128 + go * 8);
        }
    }
    __syncthreads();

    f32x4 acc[4][4];
#pragma unroll
    for (int i = 0; i < 4; ++i)
#pragma unroll
        for (int j = 0; j < 4; ++j) acc[i][j] = (f32x4){0.f, 0.f, 0.f, 0.f};
#pragma unroll
    for (int ks = 0; ks < 4; ++ks) {
        bf16x8 af[4], bfr[4];
        const int kb = ks * 64 + g * 16;
#pragma unroll
        for (int mi = 0; mi < 4; ++mi) {
            int r = wy * 64 + mi * 16 + ln;
            af[mi] = *(const bf16x8*)(As + r * 256 + (kb ^ ((r & 7) << 4)));
        }
#pragma unroll
        for (int ni = 0; ni < 4; ++ni) {
            int r = wx * 64 + ni * 16 + ln;
            bfr[ni] = *(const bf16x8*)(Bs + r * 256 + (kb ^ ((r & 7) << 4)));
        }
#pragma unroll
        for (int mi = 0; mi < 4; ++mi)
#pragma unroll
            for (int ni = 0; ni < 4; ++ni)
                acc[mi][ni] = __builtin_amdgcn_mfma_f32_16x16x32_bf16(af[mi], bfr[ni], acc[mi][ni], 0, 0, 0);
    }
    float bv[4];
#pragma unroll
    for (int ni = 0; ni < 4; ++ni) bv[ni] = b_ih[nt * 128 + wx * 64 + ni * 16 + ln];
#pragma unroll
    for (int mi = 0; mi < 4; ++mi)
#pragma unroll
        for (int jj = 0; jj < 4; ++jj) {
            int m = mt * 128 + wy * 64 + mi * 16 + g * 4 + jj;
#pragma unroll
            for (int ni = 0; ni < 4; ++ni) {
                int n = nt * 128 + wx * 64 + ni * 16 + ln;
                gi[(size_t)m * 384 + n] = acc[mi][ni][jj] + bv[ni];
            }
        }
}

// ---------------- GRU v4: bf16-packed weights (48 VGPRs) + v_dot2_f32_bf16 ----------------
// thread (g = tid>>2, q = tid&3): W_hh rows {g, g+128, g+256}, packed k-quarter q*16..+16 (u32)
// hbuf: packed bf16 h, 4 rotated copies (stride 72 u32 -> q-groups in disjoint bank quads)
__global__ __launch_bounds__(512, 2) void k_gru(const float* __restrict__ gi,
                                                const unsigned int* __restrict__ Whp,
                                                const float* __restrict__ bhh,
                                                unsigned int* __restrict__ ctxp,
                                                float* __restrict__ out_hidden) {
    const int b = blockIdx.x;
    const int tid = threadIdx.x;
    const int g = tid >> 2, q = tid & 3;
    __shared__ unsigned int hbuf[2][4][72];

    uint4 w0[4], w1[4], w2[4];
    {
        const unsigned int* W0 = Whp + (size_t)g * 64 + q * 16;
        const unsigned int* W1 = Whp + (size_t)(g + 128) * 64 + q * 16;
        const unsigned int* W2 = Whp + (size_t)(g + 256) * 64 + q * 16;
#pragma unroll
        for (int i = 0; i < 4; ++i) {
            w0[i] = ldg4u_pin(W0 + i * 4);
            w1[i] = ldg4u_pin(W1 + i * 4);
            w2[i] = ldg4u_pin(W2 + i * 4);
        }
    }
    const float bh0 = bhh[g], bh1 = bhh[g + 128], bh2 = bhh[g + 256];

    hbuf[0][q][g >> 1] = 0u;

    // depth-2 prefetch of gate pre-activations (fp32)
    float p0r = gi[(size_t)b * 384 + g];
    float p0z = gi[(size_t)b * 384 + 128 + g];
    float p0n = gi[(size_t)b * 384 + 256 + g];
    float p1r = gi[((size_t)128 + b) * 384 + g];
    float p1z = gi[((size_t)128 + b) * 384 + 128 + g];
    float p1n = gi[((size_t)128 + b) * 384 + 256 + g];
    __syncthreads();

    for (int t = 0; t < 256; ++t) {
        const int cur = t & 1;
        float p2r = 0.f, p2z = 0.f, p2n = 0.f;
        if (t + 2 < 256) {
            const float* gp = gi + ((size_t)(t + 2) * 128 + b) * 384;
            p2r = gp[g]; p2z = gp[128 + g]; p2n = gp[256 + g];
        }

        // packed h quarter (broadcast within q-group, q-groups bank-disjoint)
        const unsigned int* hc = &hbuf[cur][q][q * 16];
        uint4 h2[4];
#pragma unroll
        for (int i = 0; i < 4; ++i) h2[i] = *(const uint4*)(hc + i * 4);
        unsigned int hw = hbuf[cur][q][g >> 1];
        const float hold = (g & 1) ? b2f_hi(hw) : b2f_lo(hw);

        float a0 = 0.f, a1 = 0.f, a2 = 0.f;
#pragma unroll
        for (int i = 0; i < 4; ++i) {
            dot2b(a0, w0[i].x, h2[i].x); dot2b(a1, w1[i].x, h2[i].x); dot2b(a2, w2[i].x, h2[i].x);
            dot2b(a0, w0[i].y, h2[i].y); dot2b(a1, w1[i].y, h2[i].y); dot2b(a2, w2[i].y, h2[i].y);
            dot2b(a0, w0[i].z, h2[i].z); dot2b(a1, w1[i].z, h2[i].z); dot2b(a2, w2[i].z, h2[i].z);
            dot2b(a0, w0[i].w, h2[i].w); dot2b(a1, w1[i].w, h2[i].w); dot2b(a2, w2[i].w, h2[i].w);
        }
        a0 += __shfl_xor(a0, 1); a0 += __shfl_xor(a0, 2);
        a1 += __shfl_xor(a1, 1); a1 += __shfl_xor(a1, 2);
        a2 += __shfl_xor(a2, 1); a2 += __shfl_xor(a2, 2);

        float xr = p0r + a0 + bh0;  xr = fminf(fmaxf(xr, -60.f), 60.f);
        float xz = p0z + a1 + bh1;  xz = fminf(fmaxf(xz, -60.f), 60.f);
        float r = frcp(1.f + __expf(-xr));
        float z = frcp(1.f + __expf(-xz));
        float xn = p0n + r * (a2 + bh2); xn = fminf(fmaxf(xn, -15.f), 15.f);
        float e2 = __expf(-2.f * xn);
        float n = (1.f - e2) * frcp(1.f + e2);
        float hnew = (1.f - z) * n + z * hold;

        // pack pair (g, g+1): neighbor's hnew is 4 lanes down (same wave)
        float hn2 = __shfl_down(hnew, 4);
        if (!(g & 1)) {
            unsigned int pw = pk2(hnew, hn2);
            hbuf[cur ^ 1][q][g >> 1] = pw;                 // lane q updates copy q (1 conflict-free store)
            if (q == 0) {
                ctxp[((size_t)t * 128 + b) * 64 + (g >> 1)] = pw;
                if (t == 255) {
                    out_hidden[b * 128 + g] = hnew;
                    out_hidden[b * 128 + g + 1] = hn2;
                }
            }
        }
        p0r = p1r; p0z = p1z; p0n = p1n;
        p1r = p2r; p1z = p2z; p1n = p2n;
        __syncthreads();
    }
}

// ---------------- fused CPC: MFMA GEMM1 (P^T) -> MFMA GEMM2 (Sc) -> reg softmax ----------------
__global__ __launch_bounds__(256) void k_cpc(const unsigned short* __restrict__ ctxb,
                                             const unsigned short* __restrict__ encb,
                                             const float* __restrict__ pW,
                                             const float* __restrict__ pb,
                                             float* __restrict__ lp,
                                             float* __restrict__ cp) {
    const int s = blockIdx.x, o = blockIdx.y;
    __shared__ __align__(16) char bufA[32768];   // ctx [c][d] -> later tgt [b][e]
    __shared__ __align__(16) char bufB[32768];   // Wo  [e][d] -> later P   [c][e]
    __shared__ float rowm[2][128], rowsum[2][128];
    __shared__ float Lrow[128], diagv[128];
    __shared__ float colv[2][128];
    __shared__ int   colix[2][128];
    __shared__ float fin[4];

    const int tid = threadIdx.x;
    const int lane = tid & 63, wid = tid >> 6;
    const int wy = wid >> 1, wx = wid & 1;
    const int g = lane >> 4, ln = lane & 15;

    {
        const unsigned short* src = ctxb + (size_t)(TIn + s) * (128 * 128);
        const float* wsrc = pW + (size_t)o * (128 * 128);
#pragma unroll
        for (int it = 0; it < 8; ++it) {
            int G = tid + it * 256;
            int r = G >> 4, go = G & 15;
            *(uint4*)(bufA + (r * 16 + (go ^ (r & 7))) * 16) = *(const uint4*)(src + r * 128 + go * 8);
            float4 f0 = *(const float4*)(wsrc + r * 128 + go * 8);
            float4 f1 = *(const float4*)(wsrc + r * 128 + go * 8 + 4);
            uint4 w; w.x = pk2(f0.x, f0.y); w.y = pk2(f0.z, f0.w);
            w.z = pk2(f1.x, f1.y); w.w = pk2(f1.z, f1.w);
            *(uint4*)(bufB + (r * 16 + (go ^ (r & 7))) * 16) = w;
        }
    }
    __syncthreads();

    // GEMM1: P^T[e][c] = Wo[e][:] . ctx[c][:]
    f32x4 acc[4][4];
#pragma unroll
    for (int i = 0; i < 4; ++i)
#pragma unroll
        for (int j = 0; j < 4; ++j) acc[i][j] = (f32x4){0.f, 0.f, 0.f, 0.f};
#pragma unroll
    for (int ks = 0; ks < 4; ++ks) {
        bf16x8 af[4], bfr[4];
        const int kb = ks * 64 + g * 16;
#pragma unroll
        for (int mi = 0; mi < 4; ++mi) {
            int r = wy * 64 + mi * 16 + ln;
            af[mi] = *(const bf16x8*)(bufB + r * 256 + (kb ^ ((r & 7) << 4)));
        }
#pragma unroll
        for (int ni = 0; ni < 4; ++ni) {
            int r = wx * 64 + ni * 16 + ln;
            bfr[ni] = *(const bf16x8*)(bufA + r * 256 + (kb ^ ((r & 7) << 4)));
        }
#pragma unroll
        for (int mi = 0; mi < 4; ++mi)
#pragma unroll
            for (int ni = 0; ni < 4; ++ni)
                acc[mi][ni] = __builtin_amdgcn_mfma_f32_16x16x32_bf16(af[mi], bfr[ni], acc[mi][ni], 0, 0, 0);
    }
    __syncthreads();

    // write P[c][e] (bias, bf16, swizzled) into bufB; stage tgt into bufA
    {
        float pbv[4][4];
#pragma unroll
        for (int mi = 0; mi < 4; ++mi) {
            int e0 = wy * 64 + mi * 16 + g * 4;
#pragma unroll
            for (int jj = 0; jj < 4; ++jj) pbv[mi][jj] = pb[o * 128 + e0 + jj];
        }
#pragma unroll
        for (int mi = 0; mi < 4; ++mi) {
            int e0 = wy * 64 + mi * 16 + g * 4;
#pragma unroll
            for (int ni = 0; ni < 4; ++ni) {
                int c = wx * 64 + ni * 16 + ln;
                unsigned int lo = pk2(acc[mi][ni][0] + pbv[mi][0], acc[mi][ni][1] + pbv[mi][1]);
                unsigned int hi = pk2(acc[mi][ni][2] + pbv[mi][2], acc[mi][ni][3] + pbv[mi][3]);
                int byteoff = c * 256 + ((e0 * 2) ^ ((c & 7) << 4));
                *(uint2*)(bufB + byteoff) = make_uint2(lo, hi);
            }
        }
        const unsigned short* tsrc = encb + (size_t)(TIn + 1 + o + s) * (128 * 128);
#pragma unroll
        for (int it = 0; it < 8; ++it) {
            int G = tid + it * 256;
            int r = G >> 4, go = G & 15;
            *(uint4*)(bufA + (r * 16 + (go ^ (r & 7))) * 16) = *(const uint4*)(tsrc + r * 128 + go * 8);
        }
    }
    __syncthreads();

    // GEMM2: Sc[b][c] = tgt[b][:] . P[c][:]
#pragma unroll
    for (int i = 0; i < 4; ++i)
#pragma unroll
        for (int j = 0; j < 4; ++j) acc[i][j] = (f32x4){0.f, 0.f, 0.f, 0.f};
#pragma unroll
    for (int ks = 0; ks < 4; ++ks) {
        bf16x8 af[4], bfr[4];
        const int kb = ks * 64 + g * 16;
#pragma unroll
        for (int mi = 0; mi < 4; ++mi) {
            int r = wy * 64 + mi * 16 + ln;
            af[mi] = *(const bf16x8*)(bufA + r * 256 + (kb ^ ((r & 7) << 4)));
        }
#pragma unroll
        for (int ni = 0; ni < 4; ++ni) {
            int r = wx * 64 + ni * 16 + ln;
            bfr[ni] = *(const bf16x8*)(bufB + r * 256 + (kb ^ ((r & 7) << 4)));
        }
#pragma unroll
        for (int mi = 0; mi < 4; ++mi)
#pragma unroll
            for (int ni = 0; ni < 4; ++ni)
                acc[mi][ni] = __builtin_amdgcn_mfma_f32_16x16x32_bf16(af[mi], bfr[ni], acc[mi][ni], 0, 0, 0);
    }

    // row softmax stats + diag, in-register
#pragma unroll
    for (int mi = 0; mi < 4; ++mi) {
#pragma unroll
        for (int jj = 0; jj < 4; ++jj) {
            float m = fmaxf(fmaxf(acc[mi][0][jj], acc[mi][1][jj]),
                            fmaxf(acc[mi][2][jj], acc[mi][3][jj]));
            m = fmaxf(m, __shfl_xor(m, 1)); m = fmaxf(m, __shfl_xor(m, 2));
            m = fmaxf(m, __shfl_xor(m, 4)); m = fmaxf(m, __shfl_xor(m, 8));
            float sm = __expf(acc[mi][0][jj] - m) + __expf(acc[mi][1][jj] - m)
                     + __expf(acc[mi][2][jj] - m) + __expf(acc[mi][3][jj] - m);
            sm += __shfl_xor(sm, 1); sm += __shfl_xor(sm, 2);
            sm += __shfl_xor(sm, 4); sm += __shfl_xor(sm, 8);
            int b = wy * 64 + mi * 16 + g * 4 + jj;
            if (ln == 0) { rowm[wx][b] = m; rowsum[wx][b] = sm; }
            if (wy == wx && ln == g * 4 + jj) diagv[b] = acc[mi][mi][jj];
        }
    }
    __syncthreads();
    if (tid < 128) {
        float m0 = rowm[0][tid], m1 = rowm[1][tid];
        float mm = fmaxf(m0, m1);
        float ss = rowsum[0][tid] * __expf(m0 - mm) + rowsum[1][tid] * __expf(m1 - mm);
        Lrow[tid] = mm + __logf(ss);
    }
    __syncthreads();

    float Lr[4][4];
#pragma unroll
    for (int mi = 0; mi < 4; ++mi)
#pragma unroll
        for (int jj = 0; jj < 4; ++jj) Lr[mi][jj] = Lrow[wy * 64 + mi * 16 + g * 4 + jj];

#pragma unroll
    for (int ni = 0; ni < 4; ++ni) {
        float best = NEG_INF; int bidx = 0x7fffffff;
#pragma unroll
        for (int mi = 0; mi < 4; ++mi)
#pragma unroll
            for (int jj = 0; jj < 4; ++jj) {
                float v = acc[mi][ni][jj] - Lr[mi][jj];
                int r = wy * 64 + mi * 16 + g * 4 + jj;
                if (v > best) { best = v; bidx = r; }
            }
#pragma unroll
        for (int mask = 16; mask <= 32; mask <<= 1) {
            float ov = __shfl_xor(best, mask);
            int   oi = __shfl_xor(bidx, mask);
            if (ov > best || (ov == best && oi < bidx)) { best = ov; bidx = oi; }
        }
        if (g == 0) {
            int c = wx * 64 + ni * 16 + ln;
            colv[wy][c] = best; colix[wy][c] = bidx;
        }
    }
    __syncthreads();

    float lsum = 0.f, csum = 0.f;
    if (tid < 128) {
        lsum = diagv[tid] - Lrow[tid];
        float v0 = colv[0][tid], v1 = colv[1][tid];
        int ix = (v1 > v0) ? colix[1][tid] : colix[0][tid];
        csum = (ix == tid) ? 1.f : 0.f;
    }
#pragma unroll
    for (int off = 32; off > 0; off >>= 1) {
        lsum += __shfl_down(lsum, off);
        csum += __shfl_down(csum, off);
    }
    if (lane == 0 && wid < 2) { fin[wid] = lsum; fin[2 + wid] = csum; }
    __syncthreads();
    if (tid == 0) {
        lp[o * Sn + s] = fin[0] + fin[1];
        cp[o * Sn + s] = fin[2] + fin[3];
    }
}

// ---------------- final reduction ----------------
__global__ __launch_bounds__(256) void k_final(const float* __restrict__ lp,
                                               const float* __restrict__ cp,
                                               float* __restrict__ out) {
    __shared__ float sl[256], sc2[256];
    const int tid = threadIdx.x;
    float l = 0.f, c = 0.f;
    for (int i = tid; i < TOn * Sn; i += 256) { l += lp[i]; c += cp[i]; }
    sl[tid] = l; sc2[tid] = c;
    __syncthreads();
    for (int s = 128; s > 0; s >>= 1) {
        if (tid < s) { sl[tid] += sl[tid + s]; sc2[tid] += sc2[tid + s]; }
        __syncthreads();
    }
    if (tid == 0) {
        out[0] = sc2[0] / DENOMF;      // accuracy
        out[1] = -sl[0] / DENOMF;      // loss
    }
}

extern "C" void kernel_launch(void* const* d_in, const int* in_sizes, int n_in,
                              void* d_out, int out_size, void* d_ws, size_t ws_size,
                              hipStream_t stream) {
    const float* X      = (const float*)d_in[0];
    const float* conv_w = (const float*)d_in[1];
    const float* conv_b = (const float*)d_in[2];
    const float* W_ih   = (const float*)d_in[3];
    const float* W_hh   = (const float*)d_in[4];
    const float* b_ih   = (const float*)d_in[5];
    const float* b_hh   = (const float*)d_in[6];
    const float* pred_W = (const float*)d_in[7];
    const float* pred_b = (const float*)d_in[8];
    float* out = (float*)d_out;
    char*  ws  = (char*)d_ws;

    unsigned short* encb = (unsigned short*)(ws + OFFB_ENC);
    unsigned short* ctxb = (unsigned short*)(ws + OFFB_CTX);
    float*          gi   = (float*)(ws + OFFB_GI);
    unsigned short* BcT  = (unsigned short*)(ws + OFFB_BCT);
    unsigned short* Wt   = (unsigned short*)(ws + OFFB_WT);
    float*          lp   = (float*)(ws + OFFB_LP);
    float*          cp   = (float*)(ws + OFFB_CP);
    unsigned int*   Whp  = (unsigned int*)(ws + OFFB_WHP);

    k_prep <<<dim3(384),     dim3(256), 0, stream>>>(conv_w, BcT, W_ih, Wt, W_hh, Whp);
    k_conv <<<dim3(256),     dim3(256), 0, stream>>>(X, BcT, conv_b, encb);
    k_gi   <<<dim3(256, 3),  dim3(256), 0, stream>>>(encb, Wt, b_ih, gi);
    k_gru  <<<dim3(128),     dim3(512), 0, stream>>>(gi, Whp, b_hh, (unsigned int*)ctxb, out + 2);
    k_cpc  <<<dim3(Sn, TOn), dim3(256), 0, stream>>>(ctxb, encb, pred_W, pred_b, lp, cp);
    k_final<<<dim3(1),       dim3(256), 0, stream>>>(lp, cp, out);
}